// Round 9
// baseline (417.829 us; speedup 1.0000x reference)
//
#include <hip/hip_runtime.h>
#include <math.h>

// clDice loss, fully fused, register-strip morphology (R9).
// R8 postmortem: LDS pipe = 78% of kernel (22 b128/thread/round). R9 moves
// vertical stencil reuse into registers: each thread owns a 4-row x 8-px
// strip; per level only boundary rows (2 b128) + edge dwords (b32) cross LDS.
// ~2.3x LDS-instruction cut. No cone gating needed: out-of-cone garbage is
// never read by in-cone outputs (erode reads distance-1, cone shrinks 1/level;
// min/max of +-inf never creates NaN). OOB semantics: erode +inf, dilate -inf,
// applied with uniform precomputed masks (no divergent border path).

#define HH 1024
#define WW 1024
#define BATCH 8
#define HW (HH * WW)
#define NITER 10
#define TW 128
#define TH 32
#define AH 64            // aperture rows (halo 16 top/bottom; 12 needed)
#define CX 20            // h8 cells per aperture row (160 px; halo 16 l/r)
#define RG 16            // rowgroups
#define RR 4             // rows per thread strip
#define NT 320           // 20 cols x 16 rowgroups = 5 waves
#define NBX 8
#define NBY 32
#define NBLK (NBX * NBY * BATCH)  // 2048

typedef _Float16 h8 __attribute__((ext_vector_type(8)));
typedef _Float16 h2 __attribute__((ext_vector_type(2)));
typedef unsigned int u32;
typedef u32 u4v __attribute__((ext_vector_type(4)));

#define MIN2(a, b) __builtin_elementwise_min(a, b)
#define MAX2(a, b) __builtin_elementwise_max(a, b)

__device__ __forceinline__ u32 alignb(u32 hi, u32 lo) {
    return (u32)((((unsigned long long)hi << 32) | lo) >> 16);
}
// result[j] = v[j-1], result[0] = left-neighbor elem7 (hi half of l3)
__device__ __forceinline__ h8 shl1(h8 v, u32 l3) {
    u4v d = __builtin_bit_cast(u4v, v);
    u4v r;
    r.x = alignb(d.x, l3); r.y = alignb(d.y, d.x);
    r.z = alignb(d.z, d.y); r.w = alignb(d.w, d.z);
    return __builtin_bit_cast(h8, r);
}
// result[j] = v[j+1], result[7] = right-neighbor elem0 (lo half of r0d)
__device__ __forceinline__ h8 shr1(h8 v, u32 r0d) {
    u4v d = __builtin_bit_cast(u4v, v);
    u4v r;
    r.x = alignb(d.y, d.x); r.y = alignb(d.z, d.y);
    r.z = alignb(d.w, d.z); r.w = alignb(r0d, d.w);
    return __builtin_bit_cast(h8, r);
}
__device__ __forceinline__ float sigm(float x) { return 1.0f / (1.0f + __expf(-x)); }

__global__ __launch_bounds__(NT) void cldice_mega_kernel(const float* __restrict__ logits,
                                                         const int* __restrict__ target,
                                                         float* __restrict__ partials) {
    __shared__ h8 brow[RG][2][CX];   // [rg][0]=top row r0, [rg][1]=bottom row r0+3
    __shared__ u32 edge0[AH][CX];    // dword0 (elems 0,1) per row/cell
    __shared__ u32 edge3[AH][CX];    // dword3 (elems 6,7) per row/cell
    __shared__ float red[30];

    const int tid = threadIdx.x;
    const int c = tid % CX;
    const int rg = tid / CX;
    const int r0 = rg * RR;
    const int img = blockIdx.z;
    const int x0 = blockIdx.x * TW, y0 = blockIdx.y * TH;

    const _Float16 HIF = (_Float16)__builtin_inff();
    const _Float16 LOF = -HIF;
    const h8 HI8 = (h8)HIF;
    const h8 LO8 = (h8)LOF;
    const h2 LO2 = (h2)LOF;
    const h8 Z8 = (h8)(_Float16)0;

    const bool tileT = (rg >= 4 && rg <= 11 && c >= 2 && c <= 17);
    const int gxb = x0 - 16 + 8 * c;
    const int gy0 = y0 - 16 + r0;

    // geometry-invariant masks/flags
    bool rOOB[RR], dil[RR + 2];
#pragma unroll
    for (int k = 0; k < RR; ++k) rOOB[k] = (unsigned)(gy0 + k) >= HH;
#pragma unroll
    for (int q = 0; q < RR + 2; ++q) dil[q] = (unsigned)(gy0 - 1 + q) >= HH;
    h8 em, dm;   // erode mask (-inf in-img/+inf OOB), dilate mask (+inf/-inf)
#pragma unroll
    for (int j = 0; j < 8; ++j) {
        bool ok = (unsigned)(gxb + j) < WW;
        em[j] = ok ? LOF : HIF;
        dm[j] = ok ? HIF : LOF;
    }
    h2 dml, dmr;  // dilate masks for left elems (gxb-2,-1) / right elems (gxb+8,+9)
    dml[0] = ((unsigned)(gxb - 2) < WW) ? HIF : LOF;
    dml[1] = ((unsigned)(gxb - 1) < WW) ? HIF : LOF;
    dmr[0] = ((unsigned)(gxb + 8) < WW) ? HIF : LOF;
    dmr[1] = ((unsigned)(gxb + 9) < WW) ? HIF : LOF;

    const int cl = (c == 0) ? 0 : c - 1;
    const int cr = (c == CX - 1) ? CX - 1 : c + 1;
    const int rgu = (rg == 0) ? 0 : rg - 1;
    const int rgd = (rg == RG - 1) ? RG - 1 : rg + 1;

    h8 X[RR], p8[RR], sk[RR], skO[RR];
    h8 U, D;
    u32 eL[RR + 2], eR[RR + 2];
    float d_inter = 0.f, d_card = 0.f, d_st = 0.f;
#pragma unroll
    for (int k = 0; k < RR; ++k) { p8[k] = Z8; sk[k] = Z8; skO[k] = Z8; }

    for (int phase = 0; phase < 2; ++phase) {
        __syncthreads();  // prior reads done before load publish
        // ---- load strip (im_0), +inf out-of-image ----
#pragma unroll
        for (int k = 0; k < RR; ++k) {
            int gy = gy0 + k;
            bool gyok = (unsigned)gy < HH;
            float v[8];
            if (gyok && gxb >= 0 && gxb + 7 < WW) {
                int g = img * HW + gy * WW + gxb;
                if (phase == 0) {
                    float4 a = *(const float4*)(logits + g);
                    float4 b = *(const float4*)(logits + g + 4);
                    v[0] = sigm(a.x); v[1] = sigm(a.y); v[2] = sigm(a.z); v[3] = sigm(a.w);
                    v[4] = sigm(b.x); v[5] = sigm(b.y); v[6] = sigm(b.z); v[7] = sigm(b.w);
                } else {
                    int4 a = *(const int4*)(target + g);
                    int4 b = *(const int4*)(target + g + 4);
                    v[0] = (float)a.x; v[1] = (float)a.y; v[2] = (float)a.z; v[3] = (float)a.w;
                    v[4] = (float)b.x; v[5] = (float)b.y; v[6] = (float)b.z; v[7] = (float)b.w;
                }
            } else {
#pragma unroll
                for (int j = 0; j < 8; ++j) {
                    int gx = gxb + j;
                    if (gyok && (unsigned)gx < WW) {
                        int g = img * HW + gy * WW + gx;
                        v[j] = (phase == 0) ? sigm(logits[g]) : (float)target[g];
                    } else v[j] = INFINITY;
                }
            }
            h8 hv;
#pragma unroll
            for (int j = 0; j < 8; ++j) hv[j] = (_Float16)v[j];
            X[k] = hv;
        }
        // ---- publish im_0 boundary rows + edge dwords ----
        brow[rg][0][c] = X[0];
        brow[rg][1][c] = X[RR - 1];
#pragma unroll
        for (int k = 0; k < RR; ++k) {
            u4v q = __builtin_bit_cast(u4v, X[k]);
            edge0[r0 + k][c] = q.x;
            edge3[r0 + k][c] = q.w;
        }
        // ---- dice sums / keep probs ----
        if (tileT) {
            if (phase == 0) {
#pragma unroll
                for (int k = 0; k < RR; ++k) p8[k] = X[k];
            } else {
#pragma unroll
                for (int k = 0; k < RR; ++k)
#pragma unroll
                    for (int j = 0; j < 8; ++j) {
                        float p = (float)p8[k][j], t = (float)X[k][j];
                        d_inter += p * t;
                        d_card += p + t;
                        d_st += t;
                    }
            }
        }
        __syncthreads();
        // ---- readpass: neighbor data of im_0 ----
        { h8 t = brow[rgu][1][c]; U = (rg == 0) ? HI8 : t; }
        { h8 t = brow[rgd][0][c]; D = (rg == RG - 1) ? HI8 : t; }
#pragma unroll
        for (int q = 0; q < RR + 2; ++q) {
            int rr = r0 - 1 + q;
            rr = rr < 0 ? 0 : (rr > AH - 1 ? AH - 1 : rr);
            eL[q] = edge3[rr][cl];
            eR[q] = edge0[rr][cr];
        }

        // ---- rounds L=1..11: im_L = erode(im_{L-1}); delta_{L-1} = relu(im_{L-1}-dilate(im_L)) ----
        for (int L = 1; L <= NITER + 1; ++L) {
            __syncthreads();  // all reads of level L-1 buffers done
            h8 nw[RR];
#pragma unroll
            for (int k = 0; k < RR; ++k) {
                h8 up = (k == 0) ? U : X[k - 1];
                h8 dn = (k == RR - 1) ? D : X[k + 1];
                h8 vm = MIN2(MIN2(up, dn), X[k]);
                h8 e = MIN2(vm, MIN2(shl1(X[k], eL[k + 1]), shr1(X[k], eR[k + 1])));
                e = MAX2(e, em);
                nw[k] = rOOB[k] ? HI8 : e;
            }
            brow[rg][0][c] = nw[0];
            brow[rg][1][c] = nw[RR - 1];
#pragma unroll
            for (int k = 0; k < RR; ++k) {
                u4v q = __builtin_bit_cast(u4v, nw[k]);
                edge0[r0 + k][c] = q.x;
                edge3[r0 + k][c] = q.w;
            }
            __syncthreads();  // im_L published
            h8 Un, Dn;
            { h8 t = brow[rgu][1][c]; Un = (rg == 0) ? HI8 : t; }
            { h8 t = brow[rgd][0][c]; Dn = (rg == RG - 1) ? HI8 : t; }
            u32 eLn[RR + 2], eRn[RR + 2];
#pragma unroll
            for (int q = 0; q < RR + 2; ++q) {
                int rr = r0 - 1 + q;
                rr = rr < 0 ? 0 : (rr > AH - 1 ? AH - 1 : rr);
                eLn[q] = edge3[rr][cl];
                eRn[q] = edge0[rr][cr];
            }
            if (tileT) {
                // dilate inputs: OOB -> -inf
                h8 z[RR + 2];
                z[0] = dil[0] ? LO8 : MIN2(Un, dm);
#pragma unroll
                for (int k = 0; k < RR; ++k) z[k + 1] = dil[k + 1] ? LO8 : MIN2(nw[k], dm);
                z[RR + 1] = dil[RR + 1] ? LO8 : MIN2(Dn, dm);
                h2 zl[RR + 2], zr[RR + 2];
#pragma unroll
                for (int q = 0; q < RR + 2; ++q) {
                    h2 a = __builtin_bit_cast(h2, eLn[q]);
                    h2 b = __builtin_bit_cast(h2, eRn[q]);
                    zl[q] = dil[q] ? LO2 : MIN2(a, dml);
                    zr[q] = dil[q] ? LO2 : MIN2(b, dmr);
                }
#pragma unroll
                for (int k = 0; k < RR; ++k) {
                    h8 vm = MAX2(MAX2(z[k], z[k + 1]), z[k + 2]);
                    h2 vl = MAX2(MAX2(zl[k], zl[k + 1]), zl[k + 2]);
                    h2 vr = MAX2(MAX2(zr[k], zr[k + 1]), zr[k + 2]);
                    h8 op = MAX2(vm, MAX2(shl1(vm, __builtin_bit_cast(u32, vl)),
                                          shr1(vm, __builtin_bit_cast(u32, vr))));
                    h8 dlt = MAX2(X[k] - op, Z8);
                    if (L == 1) sk[k] = dlt;
                    else sk[k] = sk[k] + MAX2(dlt - sk[k] * dlt, Z8);
                }
            }
            // advance state
#pragma unroll
            for (int k = 0; k < RR; ++k) X[k] = nw[k];
            U = Un; D = Dn;
#pragma unroll
            for (int q = 0; q < RR + 2; ++q) { eL[q] = eLn[q]; eR[q] = eRn[q]; }
        }
        if (phase == 0) {
#pragma unroll
            for (int k = 0; k < RR; ++k) skO[k] = sk[k];
        }
    }

    // ---- cldice per-thread sums ----
    float I = 0.f, So = 0.f, St = 0.f;
#pragma unroll
    for (int k = 0; k < RR; ++k)
#pragma unroll
        for (int j = 0; j < 8; ++j) {
            float a = (float)skO[k][j], b = (float)sk[k][j];
            I += a * b; So += a; St += b;
        }

    // ---- block reduce 6 values (5 waves) ----
    float v6[6] = {d_inter, d_card, d_st, I, So, St};
#pragma unroll
    for (int q = 0; q < 6; ++q)
        for (int off = 32; off > 0; off >>= 1) v6[q] += __shfl_down(v6[q], off);
    int lane = tid & 63, w = tid >> 6;
    if (lane == 0) {
#pragma unroll
        for (int q = 0; q < 6; ++q) red[w * 6 + q] = v6[q];
    }
    __syncthreads();
    if (tid == 0) {
        int bid = (blockIdx.z * gridDim.y + blockIdx.y) * gridDim.x + blockIdx.x;
#pragma unroll
        for (int q = 0; q < 6; ++q) {
            float s = 0.f;
#pragma unroll
            for (int ww = 0; ww < 5; ++ww) s += red[ww * 6 + q];
            partials[q * NBLK + bid] = s;
        }
    }
}

__global__ __launch_bounds__(1024) void final_kernel(const float* __restrict__ partials,
                                                     float* __restrict__ out) {
    float s[6] = {0.f, 0.f, 0.f, 0.f, 0.f, 0.f};
    for (int i = threadIdx.x; i < NBLK; i += 1024) {
#pragma unroll
        for (int q = 0; q < 6; ++q) s[q] += partials[q * NBLK + i];
    }
#pragma unroll
    for (int q = 0; q < 6; ++q)
        for (int off = 32; off > 0; off >>= 1) s[q] += __shfl_down(s[q], off);
    __shared__ float red[96];
    int lane = threadIdx.x & 63, w = threadIdx.x >> 6;
    if (lane == 0) {
#pragma unroll
        for (int q = 0; q < 6; ++q) red[w * 6 + q] = s[q];
    }
    __syncthreads();
    if (threadIdx.x == 0) {
        float t[6];
#pragma unroll
        for (int q = 0; q < 6; ++q) {
            float a = 0.f;
#pragma unroll
            for (int ww = 0; ww < 16; ++ww) a += red[ww * 6 + q];
            t[q] = a;
        }
        float inter = t[0], card = t[1], sumt = t[2];
        float I = t[3], So = t[4], St = t[5];
        float score_d = (2.0f * inter + 1.0f) / fmaxf(card + 1.0f, 1e-7f);
        float dice = (1.0f - score_d) * (sumt > 0.0f ? 1.0f : 0.0f);
        float tprec = (I + 1.0f) / (So + 1.0f);
        float tsens = (I + 1.0f) / (St + 1.0f);
        float score_c = 2.0f * (tprec * tsens) / (tprec + tsens);
        float cl = (1.0f - score_c) * (St > 0.0f ? 1.0f : 0.0f);
        out[0] = 0.5f * dice + 0.5f * cl;
    }
}

extern "C" void kernel_launch(void* const* d_in, const int* in_sizes, int n_in,
                              void* d_out, int out_size, void* d_ws, size_t ws_size,
                              hipStream_t stream) {
    const float* logits = (const float*)d_in[0];
    const int* target = (const int*)d_in[1];
    float* out = (float*)d_out;
    float* partials = (float*)d_ws;  // 6*NBLK floats, fully overwritten each call

    dim3 grid(NBX, NBY, BATCH);
    cldice_mega_kernel<<<grid, NT, 0, stream>>>(logits, target, partials);
    final_kernel<<<1, 1024, 0, stream>>>(partials, out);
}

// Round 10
// 408.577 us; speedup vs baseline: 1.0226x; 1.0226x over previous
//
#include <hip/hip_runtime.h>
#include <math.h>

// clDice loss, fully fused, register-strip morphology (R10 = R9 spill-fixed).
// R9 postmortem: theory right (conflicts 2.48e7->1.08e7) but per-thread state
// exceeded the compiler's 128-VGPR occupancy heuristic -> scratch spills
// (WRITE_SIZE 385KB -> 121MB), mega 375us. R10: (1) __launch_bounds__(NT,1)
// lifts the VGPR cap; (2) cross-phase arrays p8/skO move to OWNER-PRIVATE LDS
// slots (8KB each, no barrier interaction), cutting 32 persistent VGPRs.
// Structure unchanged: each thread owns a 4-row x 8-px strip; per level only
// boundary rows (2 b128) + edge dwords (b32) cross LDS (~2.5x fewer LDS
// cycles than R8). OOB: erode +inf, dilate -inf via precomputed masks.

#define HH 1024
#define WW 1024
#define BATCH 8
#define HW (HH * WW)
#define NITER 10
#define TW 128
#define TH 32
#define AH 64            // aperture rows (halo 16 top/bottom; 12 needed)
#define CX 20            // h8 cells per aperture row (160 px; halo 16 l/r)
#define RG 16            // rowgroups
#define RR 4             // rows per thread strip
#define NT 320           // 20 cols x 16 rowgroups = 5 waves
#define NBX 8
#define NBY 32
#define NBLK (NBX * NBY * BATCH)  // 2048

typedef _Float16 h8 __attribute__((ext_vector_type(8)));
typedef _Float16 h2 __attribute__((ext_vector_type(2)));
typedef unsigned int u32;
typedef u32 u4v __attribute__((ext_vector_type(4)));

#define MIN2(a, b) __builtin_elementwise_min(a, b)
#define MAX2(a, b) __builtin_elementwise_max(a, b)

__device__ __forceinline__ u32 alignb(u32 hi, u32 lo) {
    return (u32)((((unsigned long long)hi << 32) | lo) >> 16);
}
// result[j] = v[j-1], result[0] = left-neighbor elem7 (hi half of l3)
__device__ __forceinline__ h8 shl1(h8 v, u32 l3) {
    u4v d = __builtin_bit_cast(u4v, v);
    u4v r;
    r.x = alignb(d.x, l3); r.y = alignb(d.y, d.x);
    r.z = alignb(d.z, d.y); r.w = alignb(d.w, d.z);
    return __builtin_bit_cast(h8, r);
}
// result[j] = v[j+1], result[7] = right-neighbor elem0 (lo half of r0d)
__device__ __forceinline__ h8 shr1(h8 v, u32 r0d) {
    u4v d = __builtin_bit_cast(u4v, v);
    u4v r;
    r.x = alignb(d.y, d.x); r.y = alignb(d.z, d.y);
    r.z = alignb(d.w, d.z); r.w = alignb(r0d, d.w);
    return __builtin_bit_cast(h8, r);
}
__device__ __forceinline__ float sigm(float x) { return 1.0f / (1.0f + __expf(-x)); }

__global__ __launch_bounds__(NT, 1) void cldice_mega_kernel(const float* __restrict__ logits,
                                                            const int* __restrict__ target,
                                                            float* __restrict__ partials) {
    __shared__ h8 brow[RG][2][CX];   // [rg][0]=top row r0, [rg][1]=bottom row r0+3
    __shared__ u32 edge0[AH][CX];    // dword0 (elems 0,1) per row/cell
    __shared__ u32 edge3[AH][CX];    // dword3 (elems 6,7) per row/cell
    __shared__ h8 pLDS[128 * RR];    // probs, owner-private (tile threads only)
    __shared__ h8 skOLDS[128 * RR];  // skel_o, owner-private
    __shared__ float red[30];

    const int tid = threadIdx.x;
    const int c = tid % CX;
    const int rg = tid / CX;
    const int r0 = rg * RR;
    const int img = blockIdx.z;
    const int x0 = blockIdx.x * TW, y0 = blockIdx.y * TH;

    const _Float16 HIF = (_Float16)__builtin_inff();
    const _Float16 LOF = -HIF;
    const h8 HI8 = (h8)HIF;
    const h8 LO8 = (h8)LOF;
    const h2 LO2 = (h2)LOF;
    const h8 Z8 = (h8)(_Float16)0;

    const bool tileT = (rg >= 4 && rg <= 11 && c >= 2 && c <= 17);
    const int tix = tileT ? ((rg - 4) * 16 + (c - 2)) * RR : 0;  // owner-private slot
    const int gxb = x0 - 16 + 8 * c;
    const int gy0 = y0 - 16 + r0;

    // geometry-invariant masks/flags
    bool rOOB[RR], dil[RR + 2];
#pragma unroll
    for (int k = 0; k < RR; ++k) rOOB[k] = (unsigned)(gy0 + k) >= HH;
#pragma unroll
    for (int q = 0; q < RR + 2; ++q) dil[q] = (unsigned)(gy0 - 1 + q) >= HH;
    h8 em, dm;   // erode mask (-inf in-img/+inf OOB), dilate mask (+inf/-inf)
#pragma unroll
    for (int j = 0; j < 8; ++j) {
        bool ok = (unsigned)(gxb + j) < WW;
        em[j] = ok ? LOF : HIF;
        dm[j] = ok ? HIF : LOF;
    }
    h2 dml, dmr;  // dilate masks for left elems (gxb-2,-1) / right elems (gxb+8,+9)
    dml[0] = ((unsigned)(gxb - 2) < WW) ? HIF : LOF;
    dml[1] = ((unsigned)(gxb - 1) < WW) ? HIF : LOF;
    dmr[0] = ((unsigned)(gxb + 8) < WW) ? HIF : LOF;
    dmr[1] = ((unsigned)(gxb + 9) < WW) ? HIF : LOF;

    const int cl = (c == 0) ? 0 : c - 1;
    const int cr = (c == CX - 1) ? CX - 1 : c + 1;
    const int rgu = (rg == 0) ? 0 : rg - 1;
    const int rgd = (rg == RG - 1) ? RG - 1 : rg + 1;

    h8 X[RR], sk[RR];
    h8 U, D;
    u32 eL[RR + 2], eR[RR + 2];
    float d_inter = 0.f, d_card = 0.f, d_st = 0.f;
#pragma unroll
    for (int k = 0; k < RR; ++k) sk[k] = Z8;

    for (int phase = 0; phase < 2; ++phase) {
        __syncthreads();  // prior reads done before load publish
        // ---- load strip (im_0), +inf out-of-image ----
#pragma unroll
        for (int k = 0; k < RR; ++k) {
            int gy = gy0 + k;
            bool gyok = (unsigned)gy < HH;
            float v[8];
            if (gyok && gxb >= 0 && gxb + 7 < WW) {
                int g = img * HW + gy * WW + gxb;
                if (phase == 0) {
                    float4 a = *(const float4*)(logits + g);
                    float4 b = *(const float4*)(logits + g + 4);
                    v[0] = sigm(a.x); v[1] = sigm(a.y); v[2] = sigm(a.z); v[3] = sigm(a.w);
                    v[4] = sigm(b.x); v[5] = sigm(b.y); v[6] = sigm(b.z); v[7] = sigm(b.w);
                } else {
                    int4 a = *(const int4*)(target + g);
                    int4 b = *(const int4*)(target + g + 4);
                    v[0] = (float)a.x; v[1] = (float)a.y; v[2] = (float)a.z; v[3] = (float)a.w;
                    v[4] = (float)b.x; v[5] = (float)b.y; v[6] = (float)b.z; v[7] = (float)b.w;
                }
            } else {
#pragma unroll
                for (int j = 0; j < 8; ++j) {
                    int gx = gxb + j;
                    if (gyok && (unsigned)gx < WW) {
                        int g = img * HW + gy * WW + gx;
                        v[j] = (phase == 0) ? sigm(logits[g]) : (float)target[g];
                    } else v[j] = INFINITY;
                }
            }
            h8 hv;
#pragma unroll
            for (int j = 0; j < 8; ++j) hv[j] = (_Float16)v[j];
            X[k] = hv;
        }
        // ---- publish im_0 boundary rows + edge dwords ----
        brow[rg][0][c] = X[0];
        brow[rg][1][c] = X[RR - 1];
#pragma unroll
        for (int k = 0; k < RR; ++k) {
            u4v q = __builtin_bit_cast(u4v, X[k]);
            edge0[r0 + k][c] = q.x;
            edge3[r0 + k][c] = q.w;
        }
        // ---- dice sums / stash probs in owner-private LDS ----
        if (tileT) {
            if (phase == 0) {
#pragma unroll
                for (int k = 0; k < RR; ++k) pLDS[tix + k] = X[k];
            } else {
#pragma unroll
                for (int k = 0; k < RR; ++k) {
                    h8 p8 = pLDS[tix + k];
#pragma unroll
                    for (int j = 0; j < 8; ++j) {
                        float p = (float)p8[j], t = (float)X[k][j];
                        d_inter += p * t;
                        d_card += p + t;
                        d_st += t;
                    }
                }
            }
        }
        __syncthreads();
        // ---- readpass: neighbor data of im_0 ----
        { h8 t = brow[rgu][1][c]; U = (rg == 0) ? HI8 : t; }
        { h8 t = brow[rgd][0][c]; D = (rg == RG - 1) ? HI8 : t; }
#pragma unroll
        for (int q = 0; q < RR + 2; ++q) {
            int rr = r0 - 1 + q;
            rr = rr < 0 ? 0 : (rr > AH - 1 ? AH - 1 : rr);
            eL[q] = edge3[rr][cl];
            eR[q] = edge0[rr][cr];
        }

        // ---- rounds L=1..11: im_L = erode(im_{L-1}); delta_{L-1} = relu(im_{L-1}-dilate(im_L)) ----
        for (int L = 1; L <= NITER + 1; ++L) {
            __syncthreads();  // all reads of level L-1 buffers done
            h8 nw[RR];
#pragma unroll
            for (int k = 0; k < RR; ++k) {
                h8 up = (k == 0) ? U : X[k - 1];
                h8 dn = (k == RR - 1) ? D : X[k + 1];
                h8 vm = MIN2(MIN2(up, dn), X[k]);
                h8 e = MIN2(vm, MIN2(shl1(X[k], eL[k + 1]), shr1(X[k], eR[k + 1])));
                e = MAX2(e, em);
                nw[k] = rOOB[k] ? HI8 : e;
            }
            brow[rg][0][c] = nw[0];
            brow[rg][1][c] = nw[RR - 1];
#pragma unroll
            for (int k = 0; k < RR; ++k) {
                u4v q = __builtin_bit_cast(u4v, nw[k]);
                edge0[r0 + k][c] = q.x;
                edge3[r0 + k][c] = q.w;
            }
            __syncthreads();  // im_L published
            h8 Un, Dn;
            { h8 t = brow[rgu][1][c]; Un = (rg == 0) ? HI8 : t; }
            { h8 t = brow[rgd][0][c]; Dn = (rg == RG - 1) ? HI8 : t; }
            u32 eLn[RR + 2], eRn[RR + 2];
#pragma unroll
            for (int q = 0; q < RR + 2; ++q) {
                int rr = r0 - 1 + q;
                rr = rr < 0 ? 0 : (rr > AH - 1 ? AH - 1 : rr);
                eLn[q] = edge3[rr][cl];
                eRn[q] = edge0[rr][cr];
            }
            if (tileT) {
                // dilate inputs: OOB -> -inf
                h8 z[RR + 2];
                z[0] = dil[0] ? LO8 : MIN2(Un, dm);
#pragma unroll
                for (int k = 0; k < RR; ++k) z[k + 1] = dil[k + 1] ? LO8 : MIN2(nw[k], dm);
                z[RR + 1] = dil[RR + 1] ? LO8 : MIN2(Dn, dm);
                h2 zl[RR + 2], zr[RR + 2];
#pragma unroll
                for (int q = 0; q < RR + 2; ++q) {
                    h2 a = __builtin_bit_cast(h2, eLn[q]);
                    h2 b = __builtin_bit_cast(h2, eRn[q]);
                    zl[q] = dil[q] ? LO2 : MIN2(a, dml);
                    zr[q] = dil[q] ? LO2 : MIN2(b, dmr);
                }
#pragma unroll
                for (int k = 0; k < RR; ++k) {
                    h8 vm = MAX2(MAX2(z[k], z[k + 1]), z[k + 2]);
                    h2 vl = MAX2(MAX2(zl[k], zl[k + 1]), zl[k + 2]);
                    h2 vr = MAX2(MAX2(zr[k], zr[k + 1]), zr[k + 2]);
                    h8 op = MAX2(vm, MAX2(shl1(vm, __builtin_bit_cast(u32, vl)),
                                          shr1(vm, __builtin_bit_cast(u32, vr))));
                    h8 dlt = MAX2(X[k] - op, Z8);
                    if (L == 1) sk[k] = dlt;
                    else sk[k] = sk[k] + MAX2(dlt - sk[k] * dlt, Z8);
                }
            }
            // advance state
#pragma unroll
            for (int k = 0; k < RR; ++k) X[k] = nw[k];
            U = Un; D = Dn;
#pragma unroll
            for (int q = 0; q < RR + 2; ++q) { eL[q] = eLn[q]; eR[q] = eRn[q]; }
        }
        if (phase == 0 && tileT) {
#pragma unroll
            for (int k = 0; k < RR; ++k) skOLDS[tix + k] = sk[k];
        }
    }

    // ---- cldice per-thread sums (skO from owner-private LDS) ----
    float I = 0.f, So = 0.f, St = 0.f;
    if (tileT) {
#pragma unroll
        for (int k = 0; k < RR; ++k) {
            h8 sO = skOLDS[tix + k];
#pragma unroll
            for (int j = 0; j < 8; ++j) {
                float a = (float)sO[j], b = (float)sk[k][j];
                I += a * b; So += a; St += b;
            }
        }
    }

    // ---- block reduce 6 values (5 waves) ----
    float v6[6] = {d_inter, d_card, d_st, I, So, St};
#pragma unroll
    for (int q = 0; q < 6; ++q)
        for (int off = 32; off > 0; off >>= 1) v6[q] += __shfl_down(v6[q], off);
    int lane = tid & 63, w = tid >> 6;
    if (lane == 0) {
#pragma unroll
        for (int q = 0; q < 6; ++q) red[w * 6 + q] = v6[q];
    }
    __syncthreads();
    if (tid == 0) {
        int bid = (blockIdx.z * gridDim.y + blockIdx.y) * gridDim.x + blockIdx.x;
#pragma unroll
        for (int q = 0; q < 6; ++q) {
            float s = 0.f;
#pragma unroll
            for (int ww = 0; ww < 5; ++ww) s += red[ww * 6 + q];
            partials[q * NBLK + bid] = s;
        }
    }
}

__global__ __launch_bounds__(1024) void final_kernel(const float* __restrict__ partials,
                                                     float* __restrict__ out) {
    float s[6] = {0.f, 0.f, 0.f, 0.f, 0.f, 0.f};
    for (int i = threadIdx.x; i < NBLK; i += 1024) {
#pragma unroll
        for (int q = 0; q < 6; ++q) s[q] += partials[q * NBLK + i];
    }
#pragma unroll
    for (int q = 0; q < 6; ++q)
        for (int off = 32; off > 0; off >>= 1) s[q] += __shfl_down(s[q], off);
    __shared__ float red[96];
    int lane = threadIdx.x & 63, w = threadIdx.x >> 6;
    if (lane == 0) {
#pragma unroll
        for (int q = 0; q < 6; ++q) red[w * 6 + q] = s[q];
    }
    __syncthreads();
    if (threadIdx.x == 0) {
        float t[6];
#pragma unroll
        for (int q = 0; q < 6; ++q) {
            float a = 0.f;
#pragma unroll
            for (int ww = 0; ww < 16; ++ww) a += red[ww * 6 + q];
            t[q] = a;
        }
        float inter = t[0], card = t[1], sumt = t[2];
        float I = t[3], So = t[4], St = t[5];
        float score_d = (2.0f * inter + 1.0f) / fmaxf(card + 1.0f, 1e-7f);
        float dice = (1.0f - score_d) * (sumt > 0.0f ? 1.0f : 0.0f);
        float tprec = (I + 1.0f) / (So + 1.0f);
        float tsens = (I + 1.0f) / (St + 1.0f);
        float score_c = 2.0f * (tprec * tsens) / (tprec + tsens);
        float cl = (1.0f - score_c) * (St > 0.0f ? 1.0f : 0.0f);
        out[0] = 0.5f * dice + 0.5f * cl;
    }
}

extern "C" void kernel_launch(void* const* d_in, const int* in_sizes, int n_in,
                              void* d_out, int out_size, void* d_ws, size_t ws_size,
                              hipStream_t stream) {
    const float* logits = (const float*)d_in[0];
    const int* target = (const int*)d_in[1];
    float* out = (float*)d_out;
    float* partials = (float*)d_ws;  // 6*NBLK floats, fully overwritten each call

    dim3 grid(NBX, NBY, BATCH);
    cldice_mega_kernel<<<grid, NT, 0, stream>>>(logits, target, partials);
    final_kernel<<<1, 1024, 0, stream>>>(partials, out);
}

// Round 11
// 382.441 us; speedup vs baseline: 1.0925x; 1.0683x over previous
//
#include <hip/hip_runtime.h>
#include <math.h>

// clDice loss, fully fused, register-strip morphology (R11: RR=2, no spills).
// R9/R10 postmortem: RR=4 strip state (~150 peak VGPRs) exceeded the
// allocator's 128 target -> scratch spills (WRITE 29-121MB), occupancy 14%.
// R11: RR=2 rows/thread, 640 threads (10 waves). Per-thread state halves
// (~110 peak VGPRs -> no spill), and the edge arrays are gone: all rows live
// in one rows[] LDS buffer; edge dwords are b32 reads straight from it.
// Per round/thread: 2 b128 writes + 2 b128 + 8 b32 reads for 16 px.
// OOB semantics: erode +inf, dilate -inf via precomputed column masks +
// per-row flags. Cone argument as R9: garbage outside the shrinking validity
// cone is never consumed by in-cone outputs; min/max of +-inf never NaNs.

#define HH 1024
#define WW 1024
#define BATCH 8
#define HW (HH * WW)
#define NITER 10
#define TW 128
#define TH 32
#define AH 64            // aperture rows (halo 16 top/bottom; 12 needed)
#define CX 20            // h8 cells per aperture row (160 px; halo 16 l/r)
#define RG 32            // rowgroups
#define RR 2             // rows per thread strip
#define NT 640           // 20 cols x 32 rowgroups = 10 waves
#define NBX 8
#define NBY 32
#define NBLK (NBX * NBY * BATCH)  // 2048

typedef _Float16 h8 __attribute__((ext_vector_type(8)));
typedef _Float16 h2 __attribute__((ext_vector_type(2)));
typedef unsigned int u32;
typedef u32 u4v __attribute__((ext_vector_type(4)));

#define MIN2(a, b) __builtin_elementwise_min(a, b)
#define MAX2(a, b) __builtin_elementwise_max(a, b)

__device__ __forceinline__ u32 alignb(u32 hi, u32 lo) {
    return (u32)((((unsigned long long)hi << 32) | lo) >> 16);
}
// result[j] = v[j-1]; result[0] = left-neighbor elem7 (high half of l3)
__device__ __forceinline__ h8 shl1(h8 v, u32 l3) {
    u4v d = __builtin_bit_cast(u4v, v);
    u4v r;
    r.x = alignb(d.x, l3); r.y = alignb(d.y, d.x);
    r.z = alignb(d.z, d.y); r.w = alignb(d.w, d.z);
    return __builtin_bit_cast(h8, r);
}
// result[j] = v[j+1]; result[7] = right-neighbor elem0 (low half of r0d)
__device__ __forceinline__ h8 shr1(h8 v, u32 r0d) {
    u4v d = __builtin_bit_cast(u4v, v);
    u4v r;
    r.x = alignb(d.y, d.x); r.y = alignb(d.z, d.y);
    r.z = alignb(d.w, d.z); r.w = alignb(r0d, d.w);
    return __builtin_bit_cast(h8, r);
}
__device__ __forceinline__ float sigm(float x) { return 1.0f / (1.0f + __expf(-x)); }

__global__ __launch_bounds__(NT) void cldice_mega_kernel(const float* __restrict__ logits,
                                                         const int* __restrict__ target,
                                                         float* __restrict__ partials) {
    __shared__ __align__(16) h8 rows[AH * CX];  // 20 KB: the whole aperture, one level
    __shared__ h8 pLDS[512];                    // probs, owner-private tile stash (8 KB)
    __shared__ h8 skOLDS[512];                  // skel_o, owner-private (8 KB)
    __shared__ float red[60];
    u32* rows32 = (u32*)rows;

    const int tid = threadIdx.x;
    const int c = tid % CX;      // 0..19
    const int rg = tid / CX;     // 0..31
    const int r0 = rg * RR;
    const int img = blockIdx.z;
    const int x0 = blockIdx.x * TW, y0 = blockIdx.y * TH;

    const _Float16 HIF = (_Float16)__builtin_inff();
    const _Float16 LOF = -HIF;
    const h8 HI8 = (h8)HIF;
    const h8 LO8 = (h8)LOF;
    const h2 LO2 = (h2)LOF;
    const h8 Z8 = (h8)(_Float16)0;

    const bool tileT = (rg >= 8 && rg <= 23 && c >= 2 && c <= 17);
    const int tix = tileT ? ((rg - 8) * 16 + (c - 2)) * RR : 0;
    const int gxb = x0 - 16 + 8 * c;
    const int gy0 = y0 - 16 + r0;

    // geometry-invariant masks/flags
    const bool rOOB0 = (unsigned)(gy0) >= HH;
    const bool rOOB1 = (unsigned)(gy0 + 1) >= HH;
    const bool dil0 = (unsigned)(gy0 - 1) >= HH;
    const bool dil3 = (unsigned)(gy0 + 2) >= HH;
    h8 em, dm;   // erode mask (-inf in-img / +inf OOB), dilate mask (+inf / -inf)
#pragma unroll
    for (int j = 0; j < 8; ++j) {
        bool ok = (unsigned)(gxb + j) < WW;
        em[j] = ok ? LOF : HIF;
        dm[j] = ok ? HIF : LOF;
    }
    h2 dml, dmr;  // dilate masks for edge elems (gxb-2,-1) / (gxb+8,+9)
    dml[0] = ((unsigned)(gxb - 2) < WW) ? HIF : LOF;
    dml[1] = ((unsigned)(gxb - 1) < WW) ? HIF : LOF;
    dmr[0] = ((unsigned)(gxb + 8) < WW) ? HIF : LOF;
    dmr[1] = ((unsigned)(gxb + 9) < WW) ? HIF : LOF;

    const int cl = (c == 0) ? 0 : c - 1;
    const int cr = (c == CX - 1) ? CX - 1 : c + 1;
    const int rru = (rg == 0) ? 0 : r0 - 1;
    const int rrd = (rg == RG - 1) ? AH - 1 : r0 + 2;

    h8 X0, X1, sk0, sk1, U, D;
    u32 eL[4], eR[4];   // edge dwords rows r0-1..r0+2
    float d_inter = 0.f, d_card = 0.f, d_st = 0.f;
    sk0 = Z8; sk1 = Z8;

    for (int phase = 0; phase < 2; ++phase) {
        __syncthreads();  // prior phase's reads of rows[] complete
        // ---- load strip (im_0), +inf out-of-image ----
#pragma unroll
        for (int k = 0; k < RR; ++k) {
            int gy = gy0 + k;
            bool gyok = (unsigned)gy < HH;
            float v[8];
            if (gyok && gxb >= 0 && gxb + 7 < WW) {
                int g = img * HW + gy * WW + gxb;
                if (phase == 0) {
                    float4 a = *(const float4*)(logits + g);
                    float4 b = *(const float4*)(logits + g + 4);
                    v[0] = sigm(a.x); v[1] = sigm(a.y); v[2] = sigm(a.z); v[3] = sigm(a.w);
                    v[4] = sigm(b.x); v[5] = sigm(b.y); v[6] = sigm(b.z); v[7] = sigm(b.w);
                } else {
                    int4 a = *(const int4*)(target + g);
                    int4 b = *(const int4*)(target + g + 4);
                    v[0] = (float)a.x; v[1] = (float)a.y; v[2] = (float)a.z; v[3] = (float)a.w;
                    v[4] = (float)b.x; v[5] = (float)b.y; v[6] = (float)b.z; v[7] = (float)b.w;
                }
            } else {
#pragma unroll
                for (int j = 0; j < 8; ++j) {
                    int gx = gxb + j;
                    if (gyok && (unsigned)gx < WW) {
                        int g = img * HW + gy * WW + gx;
                        v[j] = (phase == 0) ? sigm(logits[g]) : (float)target[g];
                    } else v[j] = INFINITY;
                }
            }
            h8 hv;
#pragma unroll
            for (int j = 0; j < 8; ++j) hv[j] = (_Float16)v[j];
            if (k == 0) X0 = hv; else X1 = hv;
        }
        // ---- publish im_0 + dice ----
        rows[r0 * CX + c] = X0;
        rows[(r0 + 1) * CX + c] = X1;
        if (tileT) {
            if (phase == 0) {
                pLDS[tix] = X0;
                pLDS[tix + 1] = X1;
            } else {
                h8 pa = pLDS[tix], pb = pLDS[tix + 1];
#pragma unroll
                for (int j = 0; j < 8; ++j) {
                    float p0 = (float)pa[j], t0 = (float)X0[j];
                    float p1 = (float)pb[j], t1 = (float)X1[j];
                    d_inter += p0 * t0 + p1 * t1;
                    d_card += (p0 + t0) + (p1 + t1);
                    d_st += t0 + t1;
                }
            }
        }
        __syncthreads();  // level-0 published
        // ---- readpass level 0 ----
        { h8 t = rows[rru * CX + c]; U = (rg == 0) ? HI8 : t; }
        { h8 t = rows[rrd * CX + c]; D = (rg == RG - 1) ? HI8 : t; }
#pragma unroll
        for (int q = 0; q < 4; ++q) {
            int rr = r0 - 1 + q;
            rr = rr < 0 ? 0 : (rr > AH - 1 ? AH - 1 : rr);
            eL[q] = rows32[(rr * CX + cl) * 4 + 3];
            eR[q] = rows32[(rr * CX + cr) * 4 + 0];
        }

        // ---- rounds L=1..11 ----
        for (int L = 1; L <= NITER + 1; ++L) {
            // erode (registers only)
            h8 nw0, nw1;
            {
                h8 vm0 = MIN2(MIN2(U, X1), X0);
                h8 e0 = MIN2(vm0, MIN2(shl1(X0, eL[1]), shr1(X0, eR[1])));
                nw0 = rOOB0 ? HI8 : MAX2(e0, em);
                h8 vm1 = MIN2(MIN2(X0, D), X1);
                h8 e1 = MIN2(vm1, MIN2(shl1(X1, eL[2]), shr1(X1, eR[2])));
                nw1 = rOOB1 ? HI8 : MAX2(e1, em);
            }
            __syncthreads();  // all reads of level L-1 from rows[] done
            rows[r0 * CX + c] = nw0;
            rows[(r0 + 1) * CX + c] = nw1;
            __syncthreads();  // level L published
            h8 Un, Dn;
            { h8 t = rows[rru * CX + c]; Un = (rg == 0) ? HI8 : t; }
            { h8 t = rows[rrd * CX + c]; Dn = (rg == RG - 1) ? HI8 : t; }
            u32 eLn[4], eRn[4];
#pragma unroll
            for (int q = 0; q < 4; ++q) {
                int rr = r0 - 1 + q;
                rr = rr < 0 ? 0 : (rr > AH - 1 ? AH - 1 : rr);
                eLn[q] = rows32[(rr * CX + cl) * 4 + 3];
                eRn[q] = rows32[(rr * CX + cr) * 4 + 0];
            }
            if (tileT) {
                // dilate(level L) -> open; delta_{L-1} = relu(X - open)
                h8 z0 = dil0 ? LO8 : MIN2(Un, dm);
                h8 z1 = rOOB0 ? LO8 : MIN2(nw0, dm);
                h8 z2 = rOOB1 ? LO8 : MIN2(nw1, dm);
                h8 z3 = dil3 ? LO8 : MIN2(Dn, dm);
                h8 vm0 = MAX2(MAX2(z0, z1), z2);
                h8 vm1 = MAX2(MAX2(z1, z2), z3);
                h2 zl0 = dil0 ? LO2 : MIN2(__builtin_bit_cast(h2, eLn[0]), dml);
                h2 zl1 = rOOB0 ? LO2 : MIN2(__builtin_bit_cast(h2, eLn[1]), dml);
                h2 zl2 = rOOB1 ? LO2 : MIN2(__builtin_bit_cast(h2, eLn[2]), dml);
                h2 zl3 = dil3 ? LO2 : MIN2(__builtin_bit_cast(h2, eLn[3]), dml);
                h2 zr0 = dil0 ? LO2 : MIN2(__builtin_bit_cast(h2, eRn[0]), dmr);
                h2 zr1 = rOOB0 ? LO2 : MIN2(__builtin_bit_cast(h2, eRn[1]), dmr);
                h2 zr2 = rOOB1 ? LO2 : MIN2(__builtin_bit_cast(h2, eRn[2]), dmr);
                h2 zr3 = dil3 ? LO2 : MIN2(__builtin_bit_cast(h2, eRn[3]), dmr);
                h2 vl0 = MAX2(MAX2(zl0, zl1), zl2);
                h2 vl1 = MAX2(MAX2(zl1, zl2), zl3);
                h2 vr0 = MAX2(MAX2(zr0, zr1), zr2);
                h2 vr1 = MAX2(MAX2(zr1, zr2), zr3);
                h8 op0 = MAX2(vm0, MAX2(shl1(vm0, __builtin_bit_cast(u32, vl0)),
                                        shr1(vm0, __builtin_bit_cast(u32, vr0))));
                h8 op1 = MAX2(vm1, MAX2(shl1(vm1, __builtin_bit_cast(u32, vl1)),
                                        shr1(vm1, __builtin_bit_cast(u32, vr1))));
                h8 d0 = MAX2(X0 - op0, Z8);
                h8 d1 = MAX2(X1 - op1, Z8);
                if (L == 1) { sk0 = d0; sk1 = d1; }
                else {
                    sk0 = sk0 + MAX2(d0 - sk0 * d0, Z8);
                    sk1 = sk1 + MAX2(d1 - sk1 * d1, Z8);
                }
            }
            // advance
            X0 = nw0; X1 = nw1; U = Un; D = Dn;
#pragma unroll
            for (int q = 0; q < 4; ++q) { eL[q] = eLn[q]; eR[q] = eRn[q]; }
        }
        if (phase == 0 && tileT) {
            skOLDS[tix] = sk0;
            skOLDS[tix + 1] = sk1;
        }
    }

    // ---- cldice per-thread sums ----
    float I = 0.f, So = 0.f, St = 0.f;
    if (tileT) {
        h8 sOa = skOLDS[tix], sOb = skOLDS[tix + 1];
#pragma unroll
        for (int j = 0; j < 8; ++j) {
            float a0 = (float)sOa[j], b0 = (float)sk0[j];
            float a1 = (float)sOb[j], b1 = (float)sk1[j];
            I += a0 * b0 + a1 * b1;
            So += a0 + a1;
            St += b0 + b1;
        }
    }

    // ---- block reduce 6 values (10 waves) ----
    float v6[6] = {d_inter, d_card, d_st, I, So, St};
#pragma unroll
    for (int q = 0; q < 6; ++q)
        for (int off = 32; off > 0; off >>= 1) v6[q] += __shfl_down(v6[q], off);
    int lane = tid & 63, w = tid >> 6;
    if (lane == 0) {
#pragma unroll
        for (int q = 0; q < 6; ++q) red[w * 6 + q] = v6[q];
    }
    __syncthreads();
    if (tid == 0) {
        int bid = (blockIdx.z * gridDim.y + blockIdx.y) * gridDim.x + blockIdx.x;
#pragma unroll
        for (int q = 0; q < 6; ++q) {
            float s = 0.f;
#pragma unroll
            for (int ww = 0; ww < 10; ++ww) s += red[ww * 6 + q];
            partials[q * NBLK + bid] = s;
        }
    }
}

__global__ __launch_bounds__(1024) void final_kernel(const float* __restrict__ partials,
                                                     float* __restrict__ out) {
    float s[6] = {0.f, 0.f, 0.f, 0.f, 0.f, 0.f};
    for (int i = threadIdx.x; i < NBLK; i += 1024) {
#pragma unroll
        for (int q = 0; q < 6; ++q) s[q] += partials[q * NBLK + i];
    }
#pragma unroll
    for (int q = 0; q < 6; ++q)
        for (int off = 32; off > 0; off >>= 1) s[q] += __shfl_down(s[q], off);
    __shared__ float red[96];
    int lane = threadIdx.x & 63, w = threadIdx.x >> 6;
    if (lane == 0) {
#pragma unroll
        for (int q = 0; q < 6; ++q) red[w * 6 + q] = s[q];
    }
    __syncthreads();
    if (threadIdx.x == 0) {
        float t[6];
#pragma unroll
        for (int q = 0; q < 6; ++q) {
            float a = 0.f;
#pragma unroll
            for (int ww = 0; ww < 16; ++ww) a += red[ww * 6 + q];
            t[q] = a;
        }
        float inter = t[0], card = t[1], sumt = t[2];
        float I = t[3], So = t[4], St = t[5];
        float score_d = (2.0f * inter + 1.0f) / fmaxf(card + 1.0f, 1e-7f);
        float dice = (1.0f - score_d) * (sumt > 0.0f ? 1.0f : 0.0f);
        float tprec = (I + 1.0f) / (So + 1.0f);
        float tsens = (I + 1.0f) / (St + 1.0f);
        float score_c = 2.0f * (tprec * tsens) / (tprec + tsens);
        float cl = (1.0f - score_c) * (St > 0.0f ? 1.0f : 0.0f);
        out[0] = 0.5f * dice + 0.5f * cl;
    }
}

extern "C" void kernel_launch(void* const* d_in, const int* in_sizes, int n_in,
                              void* d_out, int out_size, void* d_ws, size_t ws_size,
                              hipStream_t stream) {
    const float* logits = (const float*)d_in[0];
    const int* target = (const int*)d_in[1];
    float* out = (float*)d_out;
    float* partials = (float*)d_ws;  // 6*NBLK floats, fully overwritten each call

    dim3 grid(NBX, NBY, BATCH);
    cldice_mega_kernel<<<grid, NT, 0, stream>>>(logits, target, partials);
    final_kernel<<<1, 1024, 0, stream>>>(partials, out);
}

// Round 12
// 294.093 us; speedup vs baseline: 1.4207x; 1.3004x over previous
//
#include <hip/hip_runtime.h>
#include <math.h>

// clDice loss, fully fused (R12: phase-fused + pair-task morphology).
// R11 postmortem: register strips cost more VALU than they save in LDS;
// R8's LDS-resident structure (mega 197us, ~78% LDS-pipe) is the base.
// R12 on that base: (1) BOTH images run in the same round loop (in-place
// buffer per image: read -> barrier -> write -> barrier), halving barriers
// 44->22 and deleting the p8/skO LDS stashes (both skels accumulate in
// registers, dice computed at load); (2) tasks own horizontal CELL PAIRS:
// erode pair = 8 reads/2 cells, open pair = 12 reads/2 cells with centers
// reused as imnew. (3) halo 16px = exactly 2 cells -> all OOB masks are
// per-cell booleans (selects), no elementwise mask registers (R9/R10's
// VGPR killer). Cone gating: pair computed iff L <= pairM; element-level
// validity argument guarantees consumed elements are always freshly computed.

#define HH 1024
#define WW 1024
#define BATCH 8
#define HW (HH * WW)
#define NITER 10
#define TW 128
#define TH 32
#define AH 56                 // aperture rows (halo 12)
#define CXC 20                // h8 cells per row (160 px, halo 16 = 2 cells)
#define NCELL (AH * CXC)      // 1120
#define NE1 540               // erode pair tasks: rows 1..54 x 10 pairs
#define NT 576                // 9 waves
#define NBX 8
#define NBY 32
#define NBLK (NBX * NBY * BATCH)  // 2048

typedef _Float16 h8 __attribute__((ext_vector_type(8)));
typedef unsigned int u32;
typedef u32 u4v __attribute__((ext_vector_type(4)));

#define MIN2(a, b) __builtin_elementwise_min(a, b)
#define MAX2(a, b) __builtin_elementwise_max(a, b)

__device__ __forceinline__ u32 alignb(u32 hi, u32 lo) {
    return (u32)((((unsigned long long)hi << 32) | lo) >> 16);
}
__device__ __forceinline__ u32 dw0(h8 v) { return __builtin_bit_cast(u4v, v).x; }
__device__ __forceinline__ u32 dw3(h8 v) { return __builtin_bit_cast(u4v, v).w; }
// result[j]=v[j-1], result[0]=left-neighbor elem7 (hi half of l3)
__device__ __forceinline__ h8 shl1(h8 v, u32 l3) {
    u4v d = __builtin_bit_cast(u4v, v);
    u4v r;
    r.x = alignb(d.x, l3); r.y = alignb(d.y, d.x);
    r.z = alignb(d.z, d.y); r.w = alignb(d.w, d.z);
    return __builtin_bit_cast(h8, r);
}
// result[j]=v[j+1], result[7]=right-neighbor elem0 (lo half of r0d)
__device__ __forceinline__ h8 shr1(h8 v, u32 r0d) {
    u4v d = __builtin_bit_cast(u4v, v);
    u4v r;
    r.x = alignb(d.y, d.x); r.y = alignb(d.z, d.y);
    r.z = alignb(d.w, d.z); r.w = alignb(r0d, d.w);
    return __builtin_bit_cast(h8, r);
}
__device__ __forceinline__ float sigm(float x) { return 1.0f / (1.0f + __expf(-x)); }
__device__ __forceinline__ int imin(int a, int b) { return a < b ? a : b; }
__device__ __forceinline__ int imax(int a, int b) { return a > b ? a : b; }

// erode cell pair at base (reads 8 cells around it)
__device__ __forceinline__ void erode_pair(const h8* __restrict__ buf, int base,
                                           h8* e0, h8* e1) {
    h8 A = buf[base - 1], B0 = buf[base], B1 = buf[base + 1], C = buf[base + 2];
    h8 U0 = buf[base - CXC], U1 = buf[base - CXC + 1];
    h8 D0 = buf[base + CXC], D1 = buf[base + CXC + 1];
    *e0 = MIN2(MIN2(B0, MIN2(shl1(B0, dw3(A)), shr1(B0, dw0(B1)))), MIN2(U0, D0));
    *e1 = MIN2(MIN2(B1, MIN2(shl1(B1, dw3(B0)), shr1(B1, dw0(C)))), MIN2(U1, D1));
}

__global__ __launch_bounds__(NT) void cldice_mega_kernel(const float* __restrict__ logits,
                                                         const int* __restrict__ target,
                                                         float* __restrict__ partials) {
    __shared__ __align__(16) h8 bufO[NCELL];  // 17.9 KB
    __shared__ __align__(16) h8 bufT[NCELL];  // 17.9 KB
    __shared__ float red[54];

    const int tid = threadIdx.x;
    const int img = blockIdx.z;
    const int x0 = blockIdx.x * TW, y0 = blockIdx.y * TH;

    const _Float16 HIF = (_Float16)__builtin_inff();
    const h8 HI8 = (h8)HIF;
    const h8 LO8 = (h8)(-HIF);
    const h8 Z8 = (h8)(_Float16)0;

    // ---- e1 pair task geometry ----
    const int ep = tid;                 // pair id (< NE1)
    const int er = 1 + ep / 10;         // row 1..54
    const int epc = ep - (ep / 10) * 10;
    const int ec0 = 2 * epc;            // cell col 0..18 (even)
    const int eb = er * CXC + ec0;
    int pairM = 0;
    bool eok = false;
    if (ep < NE1) {
        int M0 = imin(imin(er, 55 - er), imin(8 * ec0 + 7, 159 - 8 * ec0));
        int M1 = imin(imin(er, 55 - er), imin(8 * ec0 + 15, 151 - 8 * ec0));
        pairM = imax(M0, M1);
        bool rowOOB = (unsigned)(y0 - 12 + er) >= HH;
        bool colOOB = (x0 == 0 && epc == 0) || (x0 == WW - TW && epc == 9);
        eok = !(rowOOB || colOOB);
    }

    // ---- open pair task geometry (tid < 256) ----
    const int tr = tid >> 3;            // 0..31
    const int opc = tid & 7;            // 0..7
    const int ro = 12 + tr;
    const int b0 = ro * CXC + 2 + 2 * opc;
    const int bm1 = b0 - CXC, bp1 = b0 + CXC;
    const bool rT = (y0 == 0 && tr == 0);
    const bool rB = (y0 == HH - TH && tr == 31);
    const bool cL = (x0 == 0 && opc == 0);
    const bool cR = (x0 == WW - TW && opc == 7);

    h8 imvO0, imvO1, imvT0, imvT1;
    h8 skO0 = Z8, skO1 = Z8, skT0 = Z8, skT1 = Z8;
    float d_inter = 0.f, d_card = 0.f, d_st = 0.f;

    // ---- load both images (level 0), +inf out-of-image ----
#pragma unroll
    for (int s = 0; s < 2; ++s) {
        int li = tid + NT * s;
        if (li < NCELL) {
            int r = li / CXC, c = li - r * CXC;
            int gy = y0 - 12 + r, gx = x0 - 16 + 8 * c;
            bool gyok = (unsigned)gy < HH;
            float vo[8], vt[8];
            if (gyok && gx >= 0 && gx + 7 < WW) {
                int g = img * HW + gy * WW + gx;
                float4 a = *(const float4*)(logits + g);
                float4 b = *(const float4*)(logits + g + 4);
                vo[0] = sigm(a.x); vo[1] = sigm(a.y); vo[2] = sigm(a.z); vo[3] = sigm(a.w);
                vo[4] = sigm(b.x); vo[5] = sigm(b.y); vo[6] = sigm(b.z); vo[7] = sigm(b.w);
                int4 p = *(const int4*)(target + g);
                int4 q = *(const int4*)(target + g + 4);
                vt[0] = (float)p.x; vt[1] = (float)p.y; vt[2] = (float)p.z; vt[3] = (float)p.w;
                vt[4] = (float)q.x; vt[5] = (float)q.y; vt[6] = (float)q.z; vt[7] = (float)q.w;
            } else {
#pragma unroll
                for (int j = 0; j < 8; ++j) {
                    int gxx = gx + j;
                    if (gyok && (unsigned)gxx < WW) {
                        int g = img * HW + gy * WW + gxx;
                        vo[j] = sigm(logits[g]);
                        vt[j] = (float)target[g];
                    } else { vo[j] = INFINITY; vt[j] = INFINITY; }
                }
            }
            h8 ho, ht;
#pragma unroll
            for (int j = 0; j < 8; ++j) { ho[j] = (_Float16)vo[j]; ht[j] = (_Float16)vt[j]; }
            bufO[li] = ho;
            bufT[li] = ht;
        }
    }
    __syncthreads();

    // ---- init: dice sums + imv (open threads read their tile pair) ----
    if (tid < 256) {
        imvO0 = bufO[b0]; imvO1 = bufO[b0 + 1];
        imvT0 = bufT[b0]; imvT1 = bufT[b0 + 1];
#pragma unroll
        for (int j = 0; j < 8; ++j) {
            float p0 = (float)imvO0[j], t0 = (float)imvT0[j];
            float p1 = (float)imvO1[j], t1 = (float)imvT1[j];
            d_inter += p0 * t0 + p1 * t1;
            d_card += (p0 + t0) + (p1 + t1);
            d_st += t0 + t1;
        }
    }

    // ---- rounds L=1..11: erode both images in place; open -> delta -> skel ----
    for (int L = 1; L <= NITER + 1; ++L) {
        const bool act = (ep < NE1) && (L <= pairM);
        h8 eO0, eO1, eT0, eT1;
        if (act) {
            erode_pair(bufO, eb, &eO0, &eO1);
            erode_pair(bufT, eb, &eT0, &eT1);
            if (!eok) { eO0 = HI8; eO1 = HI8; eT0 = HI8; eT1 = HI8; }
        }
        __syncthreads();  // all reads of level L-1 done
        if (act) {
            bufO[eb] = eO0; bufO[eb + 1] = eO1;
            bufT[eb] = eT0; bufT[eb + 1] = eT1;
        }
        __syncthreads();  // level L published
        if (tid < 256) {
            // ---- image O: open pair from level L ----
            h8 a, b, c2, ctr0, ctr1;
            a = bufO[bm1 - 1]; b = bufO[b0 - 1]; c2 = bufO[bp1 - 1];
            if (rT) a = LO8; if (rB) c2 = LO8;
            if (cL) { a = LO8; b = LO8; c2 = LO8; }
            h8 VA = MAX2(MAX2(a, b), c2);
            a = bufO[bm1]; ctr0 = bufO[b0]; c2 = bufO[bp1];
            if (rT) a = LO8; if (rB) c2 = LO8;
            h8 V0 = MAX2(MAX2(a, ctr0), c2);
            a = bufO[bm1 + 1]; ctr1 = bufO[b0 + 1]; c2 = bufO[bp1 + 1];
            if (rT) a = LO8; if (rB) c2 = LO8;
            h8 V1 = MAX2(MAX2(a, ctr1), c2);
            a = bufO[bm1 + 2]; b = bufO[b0 + 2]; c2 = bufO[bp1 + 2];
            if (rT) a = LO8; if (rB) c2 = LO8;
            if (cR) { a = LO8; b = LO8; c2 = LO8; }
            h8 VC = MAX2(MAX2(a, b), c2);
            h8 op0 = MAX2(V0, MAX2(shl1(V0, dw3(VA)), shr1(V0, dw0(V1))));
            h8 op1 = MAX2(V1, MAX2(shl1(V1, dw3(V0)), shr1(V1, dw0(VC))));
            h8 d0 = MAX2(imvO0 - op0, Z8);
            h8 d1 = MAX2(imvO1 - op1, Z8);
            if (L == 1) { skO0 = d0; skO1 = d1; }
            else {
                skO0 = skO0 + MAX2(d0 - skO0 * d0, Z8);
                skO1 = skO1 + MAX2(d1 - skO1 * d1, Z8);
            }
            imvO0 = ctr0; imvO1 = ctr1;

            // ---- image T ----
            a = bufT[bm1 - 1]; b = bufT[b0 - 1]; c2 = bufT[bp1 - 1];
            if (rT) a = LO8; if (rB) c2 = LO8;
            if (cL) { a = LO8; b = LO8; c2 = LO8; }
            VA = MAX2(MAX2(a, b), c2);
            a = bufT[bm1]; ctr0 = bufT[b0]; c2 = bufT[bp1];
            if (rT) a = LO8; if (rB) c2 = LO8;
            V0 = MAX2(MAX2(a, ctr0), c2);
            a = bufT[bm1 + 1]; ctr1 = bufT[b0 + 1]; c2 = bufT[bp1 + 1];
            if (rT) a = LO8; if (rB) c2 = LO8;
            V1 = MAX2(MAX2(a, ctr1), c2);
            a = bufT[bm1 + 2]; b = bufT[b0 + 2]; c2 = bufT[bp1 + 2];
            if (rT) a = LO8; if (rB) c2 = LO8;
            if (cR) { a = LO8; b = LO8; c2 = LO8; }
            VC = MAX2(MAX2(a, b), c2);
            op0 = MAX2(V0, MAX2(shl1(V0, dw3(VA)), shr1(V0, dw0(V1))));
            op1 = MAX2(V1, MAX2(shl1(V1, dw3(V0)), shr1(V1, dw0(VC))));
            d0 = MAX2(imvT0 - op0, Z8);
            d1 = MAX2(imvT1 - op1, Z8);
            if (L == 1) { skT0 = d0; skT1 = d1; }
            else {
                skT0 = skT0 + MAX2(d0 - skT0 * d0, Z8);
                skT1 = skT1 + MAX2(d1 - skT1 * d1, Z8);
            }
            imvT0 = ctr0; imvT1 = ctr1;
        }
        // no barrier here: open reads and next round's erode reads are both of
        // level L; next round's first barrier precedes any overwrite.
    }

    // ---- cldice per-thread sums ----
    float I = 0.f, So = 0.f, St = 0.f;
    if (tid < 256) {
#pragma unroll
        for (int j = 0; j < 8; ++j) {
            float a0 = (float)skO0[j], b0v = (float)skT0[j];
            float a1 = (float)skO1[j], b1v = (float)skT1[j];
            I += a0 * b0v + a1 * b1v;
            So += a0 + a1;
            St += b0v + b1v;
        }
    }

    // ---- block reduce 6 values (9 waves) ----
    float v6[6] = {d_inter, d_card, d_st, I, So, St};
#pragma unroll
    for (int q = 0; q < 6; ++q)
        for (int off = 32; off > 0; off >>= 1) v6[q] += __shfl_down(v6[q], off);
    int lane = tid & 63, w = tid >> 6;
    if (lane == 0) {
#pragma unroll
        for (int q = 0; q < 6; ++q) red[w * 6 + q] = v6[q];
    }
    __syncthreads();
    if (tid == 0) {
        int bid = (blockIdx.z * gridDim.y + blockIdx.y) * gridDim.x + blockIdx.x;
#pragma unroll
        for (int q = 0; q < 6; ++q) {
            float s = 0.f;
#pragma unroll
            for (int ww = 0; ww < 9; ++ww) s += red[ww * 6 + q];
            partials[q * NBLK + bid] = s;
        }
    }
}

__global__ __launch_bounds__(1024) void final_kernel(const float* __restrict__ partials,
                                                     float* __restrict__ out) {
    float s[6] = {0.f, 0.f, 0.f, 0.f, 0.f, 0.f};
    for (int i = threadIdx.x; i < NBLK; i += 1024) {
#pragma unroll
        for (int q = 0; q < 6; ++q) s[q] += partials[q * NBLK + i];
    }
#pragma unroll
    for (int q = 0; q < 6; ++q)
        for (int off = 32; off > 0; off >>= 1) s[q] += __shfl_down(s[q], off);
    __shared__ float red[96];
    int lane = threadIdx.x & 63, w = threadIdx.x >> 6;
    if (lane == 0) {
#pragma unroll
        for (int q = 0; q < 6; ++q) red[w * 6 + q] = s[q];
    }
    __syncthreads();
    if (threadIdx.x == 0) {
        float t[6];
#pragma unroll
        for (int q = 0; q < 6; ++q) {
            float a = 0.f;
#pragma unroll
            for (int ww = 0; ww < 16; ++ww) a += red[ww * 6 + q];
            t[q] = a;
        }
        float inter = t[0], card = t[1], sumt = t[2];
        float I = t[3], So = t[4], St = t[5];
        float score_d = (2.0f * inter + 1.0f) / fmaxf(card + 1.0f, 1e-7f);
        float dice = (1.0f - score_d) * (sumt > 0.0f ? 1.0f : 0.0f);
        float tprec = (I + 1.0f) / (So + 1.0f);
        float tsens = (I + 1.0f) / (St + 1.0f);
        float score_c = 2.0f * (tprec * tsens) / (tprec + tsens);
        float cl = (1.0f - score_c) * (St > 0.0f ? 1.0f : 0.0f);
        out[0] = 0.5f * dice + 0.5f * cl;
    }
}

extern "C" void kernel_launch(void* const* d_in, const int* in_sizes, int n_in,
                              void* d_out, int out_size, void* d_ws, size_t ws_size,
                              hipStream_t stream) {
    const float* logits = (const float*)d_in[0];
    const int* target = (const int*)d_in[1];
    float* out = (float*)d_out;
    float* partials = (float*)d_ws;  // 6*NBLK floats, fully overwritten each call

    dim3 grid(NBX, NBY, BATCH);
    cldice_mega_kernel<<<grid, NT, 0, stream>>>(logits, target, partials);
    final_kernel<<<1, 1024, 0, stream>>>(partials, out);
}

// Round 13
// 251.727 us; speedup vs baseline: 1.6598x; 1.1683x over previous
//
#include <hip/hip_runtime.h>
#include <math.h>

// clDice loss, fully fused (R13: phase-fused + VERTICAL pair tasks).
// R12 postmortem: horizontal pairs -> 32B thread stride -> bank conflicts
// doubled (4.9e7), negating the op cut. R13: vertical 2-row pairs keep
// thread->address stride-1 (conflict-free) while sharing reads:
// erode pair = 8 reads/2 cells, open pair = 12 reads/2 cells with shared
// vertical maxes. Both images in one round loop (in-place, 2 barriers/round),
// dice at load, skels in registers, one final LDS exchange for the skO*skT
// product. OOB is cell-granular (halo 16px = 2 cells, rows whole) ->
// boolean selects only. Cone gating per pair (L <= pairM); out-of-cone
// garbage never consumed (standard shrinking-cone argument, min/max of
// +-inf never NaNs).

#define HH 1024
#define WW 1024
#define BATCH 8
#define HW (HH * WW)
#define NITER 10
#define TW 128
#define TH 32
#define AH 56                 // aperture rows (halo 12)
#define CXC 20                // h8 cells per row (160 px, halo 16 = 2 cells)
#define NCELL (AH * CXC)      // 1120
#define NPAIR 540             // vertical erode pairs per image (27 x 20)
#define NT 512                // 8 waves
#define NBX 8
#define NBY 32
#define NBLK (NBX * NBY * BATCH)  // 2048

typedef _Float16 h8 __attribute__((ext_vector_type(8)));
typedef unsigned int u32;
typedef u32 u4v __attribute__((ext_vector_type(4)));

#define MIN2(a, b) __builtin_elementwise_min(a, b)
#define MAX2(a, b) __builtin_elementwise_max(a, b)

__device__ __forceinline__ u32 alignb(u32 hi, u32 lo) {
    return (u32)((((unsigned long long)hi << 32) | lo) >> 16);
}
__device__ __forceinline__ u32 dw0(h8 v) { return __builtin_bit_cast(u4v, v).x; }
__device__ __forceinline__ u32 dw3(h8 v) { return __builtin_bit_cast(u4v, v).w; }
// result[j]=v[j-1], result[0]=left-neighbor elem7 (hi half of l3)
__device__ __forceinline__ h8 shl1(h8 v, u32 l3) {
    u4v d = __builtin_bit_cast(u4v, v);
    u4v r;
    r.x = alignb(d.x, l3); r.y = alignb(d.y, d.x);
    r.z = alignb(d.z, d.y); r.w = alignb(d.w, d.z);
    return __builtin_bit_cast(h8, r);
}
// result[j]=v[j+1], result[7]=right-neighbor elem0 (lo half of r0d)
__device__ __forceinline__ h8 shr1(h8 v, u32 r0d) {
    u4v d = __builtin_bit_cast(u4v, v);
    u4v r;
    r.x = alignb(d.y, d.x); r.y = alignb(d.z, d.y);
    r.z = alignb(d.w, d.z); r.w = alignb(r0d, d.w);
    return __builtin_bit_cast(h8, r);
}
__device__ __forceinline__ float sigm(float x) { return 1.0f / (1.0f + __expf(-x)); }
__device__ __forceinline__ int imin(int a, int b) { return a < b ? a : b; }
__device__ __forceinline__ int imax(int a, int b) { return a > b ? a : b; }

__global__ __launch_bounds__(NT) void cldice_mega_kernel(const float* __restrict__ logits,
                                                         const int* __restrict__ target,
                                                         float* __restrict__ partials) {
    __shared__ __align__(16) h8 bufO[NCELL];  // 17.9 KB
    __shared__ __align__(16) h8 bufT[NCELL];  // 17.9 KB
    __shared__ float red[48];

    const int tid = threadIdx.x;
    const int img = blockIdx.z;
    const int x0 = blockIdx.x * TW, y0 = blockIdx.y * TH;

    const _Float16 HIF = (_Float16)__builtin_inff();
    const h8 HI8 = (h8)HIF;
    const h8 LO8 = (h8)(-HIF);
    const h8 Z8 = (h8)(_Float16)0;

    // ---- erode slot geometry (vertical pairs; 3 slots, 1080 tasks) ----
    int e_base[3], e_M[3];
    bool e_r0ok[3], e_r1ok[3], e_img[3];
#pragma unroll
    for (int s = 0; s < 3; ++s) {
        int task = tid + NT * s;
        e_M[s] = 0; e_base[s] = CXC; e_r0ok[s] = false; e_r1ok[s] = false; e_img[s] = false;
        if (task < 2 * NPAIR) {
            bool im = task >= NPAIR;
            int p = task - (im ? NPAIR : 0);
            int pr = p / 20, c = p - pr * 20;
            int r = 1 + 2 * pr;                 // rows r, r+1 (covers 1..54)
            e_base[s] = r * CXC + c;
            int cMx = imin(8 * c + 7, 159 - 8 * c);
            int M0 = imin(imin(r, 55 - r), cMx);
            int M1 = imin(imin(r + 1, 54 - r), cMx);
            e_M[s] = imax(M0, M1);
            bool colOOB = (x0 == 0 && c < 2) || (x0 == WW - TW && c >= 18);
            e_r0ok[s] = !colOOB && ((unsigned)(y0 - 12 + r) < HH);
            e_r1ok[s] = !colOOB && ((unsigned)(y0 - 12 + r + 1) < HH);
            e_img[s] = im;
        }
    }

    // ---- open geometry (vertical pairs; 512 tasks = 2 img x 256) ----
    const int op = tid & 255;
    const bool oimg = tid >= 256;
    const int opr = op >> 4, oc = op & 15;
    const int orow = 12 + 2 * opr;              // rows orow, orow+1
    const int ob = orow * CXC + 2 + oc;
    const bool rT = (y0 == 0 && opr == 0);
    const bool rB = (y0 == HH - TH && opr == 15);
    const bool cL = (x0 == 0 && oc == 0);
    const bool cR = (x0 == WW - TW && oc == 15);
    h8* obuf = oimg ? bufT : bufO;

    // ---- load both images (level 0), +inf out-of-image; dice at load ----
    float d_inter = 0.f, d_card = 0.f, d_st = 0.f;
#pragma unroll
    for (int s = 0; s < 3; ++s) {
        int li = tid + NT * s;
        if (li < NCELL) {
            int r = li / CXC, c = li - r * CXC;
            int gy = y0 - 12 + r, gx = x0 - 16 + 8 * c;
            bool gyok = (unsigned)gy < HH;
            float vo[8], vt[8];
            if (gyok && gx >= 0 && gx + 7 < WW) {
                int g = img * HW + gy * WW + gx;
                float4 a = *(const float4*)(logits + g);
                float4 b = *(const float4*)(logits + g + 4);
                vo[0] = sigm(a.x); vo[1] = sigm(a.y); vo[2] = sigm(a.z); vo[3] = sigm(a.w);
                vo[4] = sigm(b.x); vo[5] = sigm(b.y); vo[6] = sigm(b.z); vo[7] = sigm(b.w);
                int4 p = *(const int4*)(target + g);
                int4 q = *(const int4*)(target + g + 4);
                vt[0] = (float)p.x; vt[1] = (float)p.y; vt[2] = (float)p.z; vt[3] = (float)p.w;
                vt[4] = (float)q.x; vt[5] = (float)q.y; vt[6] = (float)q.z; vt[7] = (float)q.w;
            } else {
#pragma unroll
                for (int j = 0; j < 8; ++j) {
                    int gxx = gx + j;
                    if (gyok && (unsigned)gxx < WW) {
                        int g = img * HW + gy * WW + gxx;
                        vo[j] = sigm(logits[g]);
                        vt[j] = (float)target[g];
                    } else { vo[j] = INFINITY; vt[j] = INFINITY; }
                }
            }
            h8 ho, ht;
#pragma unroll
            for (int j = 0; j < 8; ++j) { ho[j] = (_Float16)vo[j]; ht[j] = (_Float16)vt[j]; }
            bufO[li] = ho;
            bufT[li] = ht;
            if (r >= 12 && r < 44 && c >= 2 && c < 18) {
#pragma unroll
                for (int j = 0; j < 8; ++j) {
                    d_inter += vo[j] * vt[j];
                    d_card += vo[j] + vt[j];
                    d_st += vt[j];
                }
            }
        }
    }
    __syncthreads();
    h8 imv0 = obuf[ob], imv1 = obuf[ob + CXC];
    h8 sk0 = Z8, sk1 = Z8;

    // ---- rounds L=1..11: erode both images in place; open -> delta -> skel ----
    for (int L = 1; L <= NITER + 1; ++L) {
        h8 eo0[3], eo1[3];
        bool act[3];
#pragma unroll
        for (int s = 0; s < 3; ++s) {
            act[s] = (L <= e_M[s]);
            if (act[s]) {
                const h8* b = e_img[s] ? bufT : bufO;
                int base = e_base[s];
                h8 u = b[base - CXC], xc0 = b[base], xc1 = b[base + CXC], d = b[base + 2 * CXC];
                h8 la = b[base - 1], ra = b[base + 1];
                h8 lb = b[base + CXC - 1], rb = b[base + CXC + 1];
                h8 v0 = MIN2(MIN2(u, xc1), xc0);
                h8 r0 = MIN2(v0, MIN2(shl1(xc0, dw3(la)), shr1(xc0, dw0(ra))));
                h8 v1 = MIN2(MIN2(xc0, d), xc1);
                h8 r1 = MIN2(v1, MIN2(shl1(xc1, dw3(lb)), shr1(xc1, dw0(rb))));
                eo0[s] = e_r0ok[s] ? r0 : HI8;
                eo1[s] = e_r1ok[s] ? r1 : HI8;
            }
        }
        __syncthreads();  // all reads of level L-1 done
#pragma unroll
        for (int s = 0; s < 3; ++s) {
            if (act[s]) {
                h8* b = e_img[s] ? bufT : bufO;
                b[e_base[s]] = eo0[s];
                b[e_base[s] + CXC] = eo1[s];
            }
        }
        __syncthreads();  // level L published
        // open pair (rows orow, orow+1) from level L
        {
            h8 l0 = obuf[ob - CXC - 1], l1 = obuf[ob - 1], l2 = obuf[ob + CXC - 1], l3 = obuf[ob + 2 * CXC - 1];
            h8 m0 = obuf[ob - CXC],     m1 = obuf[ob],     m2 = obuf[ob + CXC],     m3 = obuf[ob + 2 * CXC];
            h8 q0 = obuf[ob - CXC + 1], q1 = obuf[ob + 1], q2 = obuf[ob + CXC + 1], q3 = obuf[ob + 2 * CXC + 1];
            h8 nm1 = m1, nm2 = m2;  // level-L centers = next imv
            if (rT) { l0 = LO8; m0 = LO8; q0 = LO8; }
            if (rB) { l3 = LO8; m3 = LO8; q3 = LO8; }
            if (cL) { l0 = LO8; l1 = LO8; l2 = LO8; l3 = LO8; }
            if (cR) { q0 = LO8; q1 = LO8; q2 = LO8; q3 = LO8; }
            h8 La = MAX2(MAX2(l0, l1), l2), Lb = MAX2(MAX2(l1, l2), l3);
            h8 Ma = MAX2(MAX2(m0, m1), m2), Mb = MAX2(MAX2(m1, m2), m3);
            h8 Ra = MAX2(MAX2(q0, q1), q2), Rb = MAX2(MAX2(q1, q2), q3);
            h8 op0 = MAX2(Ma, MAX2(shl1(Ma, dw3(La)), shr1(Ma, dw0(Ra))));
            h8 op1 = MAX2(Mb, MAX2(shl1(Mb, dw3(Lb)), shr1(Mb, dw0(Rb))));
            h8 d0 = MAX2(imv0 - op0, Z8);
            h8 d1 = MAX2(imv1 - op1, Z8);
            if (L == 1) { sk0 = d0; sk1 = d1; }
            else {
                sk0 = sk0 + MAX2(d0 - sk0 * d0, Z8);
                sk1 = sk1 + MAX2(d1 - sk1 * d1, Z8);
            }
            imv0 = nm1; imv1 = nm2;
        }
        // no barrier: open reads and next round's erode reads are both level L
    }

    // ---- final skO*skT exchange (T threads publish, O threads combine) ----
    __syncthreads();
    if (oimg) { bufO[2 * op] = sk0; bufO[2 * op + 1] = sk1; }
    __syncthreads();
    float I = 0.f, So = 0.f, St = 0.f;
    if (!oimg) {
        h8 t0 = bufO[2 * op], t1 = bufO[2 * op + 1];
#pragma unroll
        for (int j = 0; j < 8; ++j) {
            float a0 = (float)sk0[j], b0 = (float)t0[j];
            float a1 = (float)sk1[j], b1 = (float)t1[j];
            I += a0 * b0 + a1 * b1;
            So += a0 + a1;
            St += b0 + b1;
        }
    }

    // ---- block reduce 6 values (8 waves) ----
    float v6[6] = {d_inter, d_card, d_st, I, So, St};
#pragma unroll
    for (int q = 0; q < 6; ++q)
        for (int off = 32; off > 0; off >>= 1) v6[q] += __shfl_down(v6[q], off);
    int lane = tid & 63, w = tid >> 6;
    if (lane == 0) {
#pragma unroll
        for (int q = 0; q < 6; ++q) red[w * 6 + q] = v6[q];
    }
    __syncthreads();
    if (tid == 0) {
        int bid = (blockIdx.z * gridDim.y + blockIdx.y) * gridDim.x + blockIdx.x;
#pragma unroll
        for (int q = 0; q < 6; ++q) {
            float s = 0.f;
#pragma unroll
            for (int ww = 0; ww < 8; ++ww) s += red[ww * 6 + q];
            partials[q * NBLK + bid] = s;
        }
    }
}

__global__ __launch_bounds__(1024) void final_kernel(const float* __restrict__ partials,
                                                     float* __restrict__ out) {
    float s[6] = {0.f, 0.f, 0.f, 0.f, 0.f, 0.f};
    for (int i = threadIdx.x; i < NBLK; i += 1024) {
#pragma unroll
        for (int q = 0; q < 6; ++q) s[q] += partials[q * NBLK + i];
    }
#pragma unroll
    for (int q = 0; q < 6; ++q)
        for (int off = 32; off > 0; off >>= 1) s[q] += __shfl_down(s[q], off);
    __shared__ float red[96];
    int lane = threadIdx.x & 63, w = threadIdx.x >> 6;
    if (lane == 0) {
#pragma unroll
        for (int q = 0; q < 6; ++q) red[w * 6 + q] = s[q];
    }
    __syncthreads();
    if (threadIdx.x == 0) {
        float t[6];
#pragma unroll
        for (int q = 0; q < 6; ++q) {
            float a = 0.f;
#pragma unroll
            for (int ww = 0; ww < 16; ++ww) a += red[ww * 6 + q];
            t[q] = a;
        }
        float inter = t[0], card = t[1], sumt = t[2];
        float I = t[3], So = t[4], St = t[5];
        float score_d = (2.0f * inter + 1.0f) / fmaxf(card + 1.0f, 1e-7f);
        float dice = (1.0f - score_d) * (sumt > 0.0f ? 1.0f : 0.0f);
        float tprec = (I + 1.0f) / (So + 1.0f);
        float tsens = (I + 1.0f) / (St + 1.0f);
        float score_c = 2.0f * (tprec * tsens) / (tprec + tsens);
        float cl = (1.0f - score_c) * (St > 0.0f ? 1.0f : 0.0f);
        out[0] = 0.5f * dice + 0.5f * cl;
    }
}

extern "C" void kernel_launch(void* const* d_in, const int* in_sizes, int n_in,
                              void* d_out, int out_size, void* d_ws, size_t ws_size,
                              hipStream_t stream) {
    const float* logits = (const float*)d_in[0];
    const int* target = (const int*)d_in[1];
    float* out = (float*)d_out;
    float* partials = (float*)d_ws;  // 6*NBLK floats, fully overwritten each call

    dim3 grid(NBX, NBY, BATCH);
    cldice_mega_kernel<<<grid, NT, 0, stream>>>(logits, target, partials);
    final_kernel<<<1, 1024, 0, stream>>>(partials, out);
}

// Round 14
// 231.079 us; speedup vs baseline: 1.8082x; 1.0894x over previous
//
#include <hip/hip_runtime.h>
#include <math.h>

// clDice loss, fully fused (R14 = R13 with 128x64 tile: less halo redundancy).
// R13 postmortem: VALU 71.7% / LDS ~116us floor, both pipes balanced; the
// remaining structural cost is halo redundancy 2.19x (aperture/tile).
// R14: tile 128x64, aperture 160x88 -> redundancy 1.72x (0.785x erode work
// per pixel), barriers amortized over 2x pixels. NT=1024 (16 waves), LDS
// 56.6 KB -> 2 blocks/CU = 32 waves/CU. Same vertical-pair machinery as R13
// (stride-1 conflict-free), both images in one round loop, in-place buffers,
// 2 barriers/round, dice at load, skels in registers.

#define HH 1024
#define WW 1024
#define BATCH 8
#define HW (HH * WW)
#define NITER 10
#define TW 128
#define TH 64
#define AH 88                 // aperture rows (halo 12)
#define CXC 20                // h8 cells per row (160 px, halo 16 = 2 cells)
#define NCELL (AH * CXC)      // 1760
#define NPAIR 860             // vertical erode pairs per image (43 x 20)
#define NT 1024               // 16 waves
#define NBX 8
#define NBY 16
#define NBLK (NBX * NBY * BATCH)  // 1024

typedef _Float16 h8 __attribute__((ext_vector_type(8)));
typedef unsigned int u32;
typedef u32 u4v __attribute__((ext_vector_type(4)));

#define MIN2(a, b) __builtin_elementwise_min(a, b)
#define MAX2(a, b) __builtin_elementwise_max(a, b)

__device__ __forceinline__ u32 alignb(u32 hi, u32 lo) {
    return (u32)((((unsigned long long)hi << 32) | lo) >> 16);
}
__device__ __forceinline__ u32 dw0(h8 v) { return __builtin_bit_cast(u4v, v).x; }
__device__ __forceinline__ u32 dw3(h8 v) { return __builtin_bit_cast(u4v, v).w; }
// result[j]=v[j-1], result[0]=left-neighbor elem7 (hi half of l3)
__device__ __forceinline__ h8 shl1(h8 v, u32 l3) {
    u4v d = __builtin_bit_cast(u4v, v);
    u4v r;
    r.x = alignb(d.x, l3); r.y = alignb(d.y, d.x);
    r.z = alignb(d.z, d.y); r.w = alignb(d.w, d.z);
    return __builtin_bit_cast(h8, r);
}
// result[j]=v[j+1], result[7]=right-neighbor elem0 (lo half of r0d)
__device__ __forceinline__ h8 shr1(h8 v, u32 r0d) {
    u4v d = __builtin_bit_cast(u4v, v);
    u4v r;
    r.x = alignb(d.y, d.x); r.y = alignb(d.z, d.y);
    r.z = alignb(d.w, d.z); r.w = alignb(r0d, d.w);
    return __builtin_bit_cast(h8, r);
}
__device__ __forceinline__ float sigm(float x) { return 1.0f / (1.0f + __expf(-x)); }
__device__ __forceinline__ int imin(int a, int b) { return a < b ? a : b; }
__device__ __forceinline__ int imax(int a, int b) { return a > b ? a : b; }

__global__ __launch_bounds__(NT) void cldice_mega_kernel(const float* __restrict__ logits,
                                                         const int* __restrict__ target,
                                                         float* __restrict__ partials) {
    __shared__ __align__(16) h8 bufO[NCELL];  // 28.2 KB
    __shared__ __align__(16) h8 bufT[NCELL];  // 28.2 KB
    __shared__ float red[96];

    const int tid = threadIdx.x;
    const int img = blockIdx.z;
    const int x0 = blockIdx.x * TW, y0 = blockIdx.y * TH;

    const _Float16 HIF = (_Float16)__builtin_inff();
    const h8 HI8 = (h8)HIF;
    const h8 LO8 = (h8)(-HIF);
    const h8 Z8 = (h8)(_Float16)0;

    // ---- erode slot geometry (vertical pairs; 2 slots, 1720 tasks) ----
    int e_base[2], e_M[2];
    bool e_r0ok[2], e_r1ok[2], e_img[2];
#pragma unroll
    for (int s = 0; s < 2; ++s) {
        int task = tid + NT * s;
        e_M[s] = 0; e_base[s] = CXC; e_r0ok[s] = false; e_r1ok[s] = false; e_img[s] = false;
        if (task < 2 * NPAIR) {
            bool im = task >= NPAIR;
            int p = task - (im ? NPAIR : 0);
            int pr = p / 20, c = p - pr * 20;
            int r = 1 + 2 * pr;                 // rows r, r+1 (covers 1..86)
            e_base[s] = r * CXC + c;
            int cMx = imin(8 * c + 7, 159 - 8 * c);
            int M0 = imin(imin(r, 87 - r), cMx);
            int M1 = imin(imin(r + 1, 86 - r), cMx);
            e_M[s] = imax(M0, M1);
            bool colOOB = (x0 == 0 && c < 2) || (x0 == WW - TW && c >= 18);
            e_r0ok[s] = !colOOB && ((unsigned)(y0 - 12 + r) < HH);
            e_r1ok[s] = !colOOB && ((unsigned)(y0 - 12 + r + 1) < HH);
            e_img[s] = im;
        }
    }

    // ---- open geometry (vertical pairs; 1024 tasks = 2 img x 512) ----
    const int op = tid & 511;
    const bool oimg = tid >= 512;
    const int opr = op >> 4, oc = op & 15;      // opr 0..31, oc 0..15
    const int orow = 12 + 2 * opr;              // rows orow, orow+1 (12..75)
    const int ob = orow * CXC + 2 + oc;
    const bool rT = (y0 == 0 && opr == 0);
    const bool rB = (y0 == HH - TH && opr == 31);
    const bool cL = (x0 == 0 && oc == 0);
    const bool cR = (x0 == WW - TW && oc == 15);
    h8* obuf = oimg ? bufT : bufO;

    // ---- load both images (level 0), +inf out-of-image; dice at load ----
    float d_inter = 0.f, d_card = 0.f, d_st = 0.f;
#pragma unroll
    for (int s = 0; s < 2; ++s) {
        int li = tid + NT * s;
        if (li < NCELL) {
            int r = li / CXC, c = li - r * CXC;
            int gy = y0 - 12 + r, gx = x0 - 16 + 8 * c;
            bool gyok = (unsigned)gy < HH;
            float vo[8], vt[8];
            if (gyok && gx >= 0 && gx + 7 < WW) {
                int g = img * HW + gy * WW + gx;
                float4 a = *(const float4*)(logits + g);
                float4 b = *(const float4*)(logits + g + 4);
                vo[0] = sigm(a.x); vo[1] = sigm(a.y); vo[2] = sigm(a.z); vo[3] = sigm(a.w);
                vo[4] = sigm(b.x); vo[5] = sigm(b.y); vo[6] = sigm(b.z); vo[7] = sigm(b.w);
                int4 p = *(const int4*)(target + g);
                int4 q = *(const int4*)(target + g + 4);
                vt[0] = (float)p.x; vt[1] = (float)p.y; vt[2] = (float)p.z; vt[3] = (float)p.w;
                vt[4] = (float)q.x; vt[5] = (float)q.y; vt[6] = (float)q.z; vt[7] = (float)q.w;
            } else {
#pragma unroll
                for (int j = 0; j < 8; ++j) {
                    int gxx = gx + j;
                    if (gyok && (unsigned)gxx < WW) {
                        int g = img * HW + gy * WW + gxx;
                        vo[j] = sigm(logits[g]);
                        vt[j] = (float)target[g];
                    } else { vo[j] = INFINITY; vt[j] = INFINITY; }
                }
            }
            h8 ho, ht;
#pragma unroll
            for (int j = 0; j < 8; ++j) { ho[j] = (_Float16)vo[j]; ht[j] = (_Float16)vt[j]; }
            bufO[li] = ho;
            bufT[li] = ht;
            if (r >= 12 && r < 76 && c >= 2 && c < 18) {
#pragma unroll
                for (int j = 0; j < 8; ++j) {
                    d_inter += vo[j] * vt[j];
                    d_card += vo[j] + vt[j];
                    d_st += vt[j];
                }
            }
        }
    }
    __syncthreads();
    h8 imv0 = obuf[ob], imv1 = obuf[ob + CXC];
    h8 sk0 = Z8, sk1 = Z8;

    // ---- rounds L=1..11: erode both images in place; open -> delta -> skel ----
    for (int L = 1; L <= NITER + 1; ++L) {
        h8 eo0[2], eo1[2];
        bool act[2];
#pragma unroll
        for (int s = 0; s < 2; ++s) {
            act[s] = (L <= e_M[s]);
            if (act[s]) {
                const h8* b = e_img[s] ? bufT : bufO;
                int base = e_base[s];
                h8 u = b[base - CXC], xc0 = b[base], xc1 = b[base + CXC], d = b[base + 2 * CXC];
                h8 la = b[base - 1], ra = b[base + 1];
                h8 lb = b[base + CXC - 1], rb = b[base + CXC + 1];
                h8 v0 = MIN2(MIN2(u, xc1), xc0);
                h8 r0 = MIN2(v0, MIN2(shl1(xc0, dw3(la)), shr1(xc0, dw0(ra))));
                h8 v1 = MIN2(MIN2(xc0, d), xc1);
                h8 r1 = MIN2(v1, MIN2(shl1(xc1, dw3(lb)), shr1(xc1, dw0(rb))));
                eo0[s] = e_r0ok[s] ? r0 : HI8;
                eo1[s] = e_r1ok[s] ? r1 : HI8;
            }
        }
        __syncthreads();  // all reads of level L-1 done
#pragma unroll
        for (int s = 0; s < 2; ++s) {
            if (act[s]) {
                h8* b = e_img[s] ? bufT : bufO;
                b[e_base[s]] = eo0[s];
                b[e_base[s] + CXC] = eo1[s];
            }
        }
        __syncthreads();  // level L published
        // open pair (rows orow, orow+1) from level L
        {
            h8 l0 = obuf[ob - CXC - 1], l1 = obuf[ob - 1], l2 = obuf[ob + CXC - 1], l3 = obuf[ob + 2 * CXC - 1];
            h8 m0 = obuf[ob - CXC],     m1 = obuf[ob],     m2 = obuf[ob + CXC],     m3 = obuf[ob + 2 * CXC];
            h8 q0 = obuf[ob - CXC + 1], q1 = obuf[ob + 1], q2 = obuf[ob + CXC + 1], q3 = obuf[ob + 2 * CXC + 1];
            h8 nm1 = m1, nm2 = m2;  // level-L centers = next imv
            if (rT) { l0 = LO8; m0 = LO8; q0 = LO8; }
            if (rB) { l3 = LO8; m3 = LO8; q3 = LO8; }
            if (cL) { l0 = LO8; l1 = LO8; l2 = LO8; l3 = LO8; }
            if (cR) { q0 = LO8; q1 = LO8; q2 = LO8; q3 = LO8; }
            h8 La = MAX2(MAX2(l0, l1), l2), Lb = MAX2(MAX2(l1, l2), l3);
            h8 Ma = MAX2(MAX2(m0, m1), m2), Mb = MAX2(MAX2(m1, m2), m3);
            h8 Ra = MAX2(MAX2(q0, q1), q2), Rb = MAX2(MAX2(q1, q2), q3);
            h8 op0 = MAX2(Ma, MAX2(shl1(Ma, dw3(La)), shr1(Ma, dw0(Ra))));
            h8 op1 = MAX2(Mb, MAX2(shl1(Mb, dw3(Lb)), shr1(Mb, dw0(Rb))));
            h8 d0 = MAX2(imv0 - op0, Z8);
            h8 d1 = MAX2(imv1 - op1, Z8);
            if (L == 1) { sk0 = d0; sk1 = d1; }
            else {
                sk0 = sk0 + MAX2(d0 - sk0 * d0, Z8);
                sk1 = sk1 + MAX2(d1 - sk1 * d1, Z8);
            }
            imv0 = nm1; imv1 = nm2;
        }
        // no barrier: open reads and next round's erode reads are both level L
    }

    // ---- final skO*skT exchange (T threads publish, O threads combine) ----
    __syncthreads();
    if (oimg) { bufO[2 * op] = sk0; bufO[2 * op + 1] = sk1; }
    __syncthreads();
    float I = 0.f, So = 0.f, St = 0.f;
    if (!oimg) {
        h8 t0 = bufO[2 * op], t1 = bufO[2 * op + 1];
#pragma unroll
        for (int j = 0; j < 8; ++j) {
            float a0 = (float)sk0[j], b0 = (float)t0[j];
            float a1 = (float)sk1[j], b1 = (float)t1[j];
            I += a0 * b0 + a1 * b1;
            So += a0 + a1;
            St += b0 + b1;
        }
    }

    // ---- block reduce 6 values (16 waves) ----
    float v6[6] = {d_inter, d_card, d_st, I, So, St};
#pragma unroll
    for (int q = 0; q < 6; ++q)
        for (int off = 32; off > 0; off >>= 1) v6[q] += __shfl_down(v6[q], off);
    int lane = tid & 63, w = tid >> 6;
    if (lane == 0) {
#pragma unroll
        for (int q = 0; q < 6; ++q) red[w * 6 + q] = v6[q];
    }
    __syncthreads();
    if (tid == 0) {
        int bid = (blockIdx.z * gridDim.y + blockIdx.y) * gridDim.x + blockIdx.x;
#pragma unroll
        for (int q = 0; q < 6; ++q) {
            float s = 0.f;
#pragma unroll
            for (int ww = 0; ww < 16; ++ww) s += red[ww * 6 + q];
            partials[q * NBLK + bid] = s;
        }
    }
}

__global__ __launch_bounds__(1024) void final_kernel(const float* __restrict__ partials,
                                                     float* __restrict__ out) {
    float s[6] = {0.f, 0.f, 0.f, 0.f, 0.f, 0.f};
    for (int i = threadIdx.x; i < NBLK; i += 1024) {
#pragma unroll
        for (int q = 0; q < 6; ++q) s[q] += partials[q * NBLK + i];
    }
#pragma unroll
    for (int q = 0; q < 6; ++q)
        for (int off = 32; off > 0; off >>= 1) s[q] += __shfl_down(s[q], off);
    __shared__ float red[96];
    int lane = threadIdx.x & 63, w = threadIdx.x >> 6;
    if (lane == 0) {
#pragma unroll
        for (int q = 0; q < 6; ++q) red[w * 6 + q] = s[q];
    }
    __syncthreads();
    if (threadIdx.x == 0) {
        float t[6];
#pragma unroll
        for (int q = 0; q < 6; ++q) {
            float a = 0.f;
#pragma unroll
            for (int ww = 0; ww < 16; ++ww) a += red[ww * 6 + q];
            t[q] = a;
        }
        float inter = t[0], card = t[1], sumt = t[2];
        float I = t[3], So = t[4], St = t[5];
        float score_d = (2.0f * inter + 1.0f) / fmaxf(card + 1.0f, 1e-7f);
        float dice = (1.0f - score_d) * (sumt > 0.0f ? 1.0f : 0.0f);
        float tprec = (I + 1.0f) / (So + 1.0f);
        float tsens = (I + 1.0f) / (St + 1.0f);
        float score_c = 2.0f * (tprec * tsens) / (tprec + tsens);
        float cl = (1.0f - score_c) * (St > 0.0f ? 1.0f : 0.0f);
        out[0] = 0.5f * dice + 0.5f * cl;
    }
}

extern "C" void kernel_launch(void* const* d_in, const int* in_sizes, int n_in,
                              void* d_out, int out_size, void* d_ws, size_t ws_size,
                              hipStream_t stream) {
    const float* logits = (const float*)d_in[0];
    const int* target = (const int*)d_in[1];
    float* out = (float*)d_out;
    float* partials = (float*)d_ws;  // 6*NBLK floats, fully overwritten each call

    dim3 grid(NBX, NBY, BATCH);
    cldice_mega_kernel<<<grid, NT, 0, stream>>>(logits, target, partials);
    final_kernel<<<1, 1024, 0, stream>>>(partials, out);
}

// Round 15
// 224.880 us; speedup vs baseline: 1.8580x; 1.0276x over previous
//
#include <hip/hip_runtime.h>
#include <math.h>

// clDice loss, fully fused (R15 = R14 with vertical QUAD tasks).
// R14 postmortem: LDS ~101us and VALU ~102us both vs mega 162us -- balanced;
// cut both via taller tasks. Erode quad: 14 reads + 4 writes per 4 cells
// (vs 16+4), shared vertical mins. Open quad: 18 reads per 4 rows (vs 24),
// shared column maxes. Erode = 880 single-slot tasks; open = 512 tasks
// (2 img x 16 row-quads x 16 cells). Same tile 128x64, aperture 160x88,
// 2 barriers/round, in-place per-image buffers, dice at load, skels in regs.
// Overlapping last erode quad (rows 83..86 vs 81..84) double-writes identical
// values between the same barriers -- benign. Cone/OOB arguments as R13/R14.

#define HH 1024
#define WW 1024
#define BATCH 8
#define HW (HH * WW)
#define NITER 10
#define TW 128
#define TH 64
#define AH 88                 // aperture rows (halo 12)
#define CXC 20                // h8 cells per row (160 px, halo 16 = 2 cells)
#define NCELL (AH * CXC)      // 1760
#define NQ 440                // erode quads per image (22 x 20)
#define NT 1024               // 16 waves
#define NBX 8
#define NBY 16
#define NBLK (NBX * NBY * BATCH)  // 1024

typedef _Float16 h8 __attribute__((ext_vector_type(8)));
typedef unsigned int u32;
typedef u32 u4v __attribute__((ext_vector_type(4)));

#define MIN2(a, b) __builtin_elementwise_min(a, b)
#define MAX2(a, b) __builtin_elementwise_max(a, b)

__device__ __forceinline__ u32 alignb(u32 hi, u32 lo) {
    return (u32)((((unsigned long long)hi << 32) | lo) >> 16);
}
__device__ __forceinline__ u32 dw0(h8 v) { return __builtin_bit_cast(u4v, v).x; }
__device__ __forceinline__ u32 dw3(h8 v) { return __builtin_bit_cast(u4v, v).w; }
// result[j]=v[j-1], result[0]=left-neighbor elem7 (hi half of l3)
__device__ __forceinline__ h8 shl1(h8 v, u32 l3) {
    u4v d = __builtin_bit_cast(u4v, v);
    u4v r;
    r.x = alignb(d.x, l3); r.y = alignb(d.y, d.x);
    r.z = alignb(d.z, d.y); r.w = alignb(d.w, d.z);
    return __builtin_bit_cast(h8, r);
}
// result[j]=v[j+1], result[7]=right-neighbor elem0 (lo half of r0d)
__device__ __forceinline__ h8 shr1(h8 v, u32 r0d) {
    u4v d = __builtin_bit_cast(u4v, v);
    u4v r;
    r.x = alignb(d.y, d.x); r.y = alignb(d.z, d.y);
    r.z = alignb(d.w, d.z); r.w = alignb(r0d, d.w);
    return __builtin_bit_cast(h8, r);
}
__device__ __forceinline__ float sigm(float x) { return 1.0f / (1.0f + __expf(-x)); }
__device__ __forceinline__ int imin(int a, int b) { return a < b ? a : b; }
__device__ __forceinline__ int imax(int a, int b) { return a > b ? a : b; }

__global__ __launch_bounds__(NT) void cldice_mega_kernel(const float* __restrict__ logits,
                                                         const int* __restrict__ target,
                                                         float* __restrict__ partials) {
    __shared__ __align__(16) h8 bufO[NCELL];  // 28.2 KB
    __shared__ __align__(16) h8 bufT[NCELL];  // 28.2 KB
    __shared__ float red[96];

    const int tid = threadIdx.x;
    const int img = blockIdx.z;
    const int x0 = blockIdx.x * TW, y0 = blockIdx.y * TH;

    const _Float16 HIF = (_Float16)__builtin_inff();
    const h8 HI8 = (h8)HIF;
    const h8 LO8 = (h8)(-HIF);
    const h8 Z8 = (h8)(_Float16)0;

    // ---- erode quad geometry (1 slot; 880 tasks) ----
    const bool has_e = tid < 2 * NQ;
    const bool e_im = tid >= NQ;
    int e_base = CXC, e_M = 0;
    bool e_rok[4] = {false, false, false, false};
    if (has_e) {
        int p = e_im ? tid - NQ : tid;
        int q = p / 20, c = p - (p / 20) * 20;
        int r = 1 + 4 * q;
        if (r > 83) r = 83;                 // last quad rows 83..86
        e_base = r * CXC + c;
        int cMx = imin(8 * c + 7, 159 - 8 * c);
#pragma unroll
        for (int k = 0; k < 4; ++k)
            e_M = imax(e_M, imin(imin(r + k, 87 - (r + k)), cMx));
        bool colOOB = (x0 == 0 && c < 2) || (x0 == WW - TW && c >= 18);
#pragma unroll
        for (int k = 0; k < 4; ++k)
            e_rok[k] = !colOOB && ((unsigned)(y0 - 12 + r + k) < HH);
    }

    // ---- open quad geometry (512 tasks = 2 img x 16 row-quads x 16 cells) ----
    const bool has_o = tid < 512;
    const int op = tid & 255;
    const bool oimg = (tid >= 256) && has_o;
    const int opr = op >> 4, oc = op & 15;      // opr 0..15, oc 0..15
    const int orow = 12 + 4 * opr;              // rows orow..orow+3 (12..75)
    const int ob = orow * CXC + 2 + oc;
    const bool rT = (y0 == 0 && opr == 0);
    const bool rB = (y0 == HH - TH && opr == 15);
    const bool cL = (x0 == 0 && oc == 0);
    const bool cR = (x0 == WW - TW && oc == 15);
    h8* obuf = oimg ? bufT : bufO;

    // ---- load both images (level 0), +inf out-of-image; dice at load ----
    float d_inter = 0.f, d_card = 0.f, d_st = 0.f;
#pragma unroll
    for (int s = 0; s < 2; ++s) {
        int li = tid + NT * s;
        if (li < NCELL) {
            int r = li / CXC, c = li - r * CXC;
            int gy = y0 - 12 + r, gx = x0 - 16 + 8 * c;
            bool gyok = (unsigned)gy < HH;
            float vo[8], vt[8];
            if (gyok && gx >= 0 && gx + 7 < WW) {
                int g = img * HW + gy * WW + gx;
                float4 a = *(const float4*)(logits + g);
                float4 b = *(const float4*)(logits + g + 4);
                vo[0] = sigm(a.x); vo[1] = sigm(a.y); vo[2] = sigm(a.z); vo[3] = sigm(a.w);
                vo[4] = sigm(b.x); vo[5] = sigm(b.y); vo[6] = sigm(b.z); vo[7] = sigm(b.w);
                int4 p = *(const int4*)(target + g);
                int4 q = *(const int4*)(target + g + 4);
                vt[0] = (float)p.x; vt[1] = (float)p.y; vt[2] = (float)p.z; vt[3] = (float)p.w;
                vt[4] = (float)q.x; vt[5] = (float)q.y; vt[6] = (float)q.z; vt[7] = (float)q.w;
            } else {
#pragma unroll
                for (int j = 0; j < 8; ++j) {
                    int gxx = gx + j;
                    if (gyok && (unsigned)gxx < WW) {
                        int g = img * HW + gy * WW + gxx;
                        vo[j] = sigm(logits[g]);
                        vt[j] = (float)target[g];
                    } else { vo[j] = INFINITY; vt[j] = INFINITY; }
                }
            }
            h8 ho, ht;
#pragma unroll
            for (int j = 0; j < 8; ++j) { ho[j] = (_Float16)vo[j]; ht[j] = (_Float16)vt[j]; }
            bufO[li] = ho;
            bufT[li] = ht;
            if (r >= 12 && r < 76 && c >= 2 && c < 18) {
#pragma unroll
                for (int j = 0; j < 8; ++j) {
                    d_inter += vo[j] * vt[j];
                    d_card += vo[j] + vt[j];
                    d_st += vt[j];
                }
            }
        }
    }
    __syncthreads();
    h8 imv[4], sk[4];
    if (has_o) {
#pragma unroll
        for (int k = 0; k < 4; ++k) imv[k] = obuf[ob + k * CXC];
    }
#pragma unroll
    for (int k = 0; k < 4; ++k) sk[k] = Z8;

    // ---- rounds L=1..11: erode both images in place; open -> delta -> skel ----
    for (int L = 1; L <= NITER + 1; ++L) {
        h8 eo[4];
        const bool act = has_e && (L <= e_M);
        if (act) {
            const h8* b = e_im ? bufT : bufO;
            h8 u  = b[e_base - CXC];
            h8 c0 = b[e_base],           c1 = b[e_base + CXC];
            h8 c2 = b[e_base + 2 * CXC], c3 = b[e_base + 3 * CXC];
            h8 d  = b[e_base + 4 * CXC];
            h8 l0 = b[e_base - 1],           l1 = b[e_base + CXC - 1];
            h8 l2 = b[e_base + 2 * CXC - 1], l3 = b[e_base + 3 * CXC - 1];
            h8 r0 = b[e_base + 1],           r1 = b[e_base + CXC + 1];
            h8 r2 = b[e_base + 2 * CXC + 1], r3 = b[e_base + 3 * CXC + 1];
            h8 p01 = MIN2(c0, c1), p12 = MIN2(c1, c2), p23 = MIN2(c2, c3);
            h8 v0 = MIN2(u, p01), v1 = MIN2(p01, c2), v2 = MIN2(p12, c3), v3 = MIN2(p23, d);
            eo[0] = MIN2(v0, MIN2(shl1(c0, dw3(l0)), shr1(c0, dw0(r0))));
            eo[1] = MIN2(v1, MIN2(shl1(c1, dw3(l1)), shr1(c1, dw0(r1))));
            eo[2] = MIN2(v2, MIN2(shl1(c2, dw3(l2)), shr1(c2, dw0(r2))));
            eo[3] = MIN2(v3, MIN2(shl1(c3, dw3(l3)), shr1(c3, dw0(r3))));
        }
        __syncthreads();  // all reads of level L-1 done
        if (act) {
            h8* b = e_im ? bufT : bufO;
#pragma unroll
            for (int k = 0; k < 4; ++k)
                b[e_base + k * CXC] = e_rok[k] ? eo[k] : HI8;
        }
        __syncthreads();  // level L published
        if (has_o) {
            // center column rows orow-1..orow+4
            h8 m0 = obuf[ob - CXC], m1 = obuf[ob], m2 = obuf[ob + CXC];
            h8 m3 = obuf[ob + 2 * CXC], m4 = obuf[ob + 3 * CXC], m5 = obuf[ob + 4 * CXC];
            h8 nm0 = m1, nm1 = m2, nm2 = m3, nm3 = m4;  // level-L centers (unmasked)
            if (rT) m0 = LO8;
            if (rB) m5 = LO8;
            h8 q12 = MAX2(m1, m2), q34 = MAX2(m3, m4);
            h8 Mc0 = MAX2(m0, q12), Mc1 = MAX2(q12, m3);
            h8 Mc2 = MAX2(m2, q34), Mc3 = MAX2(q34, m5);
            // left column
            h8 a0 = obuf[ob - CXC - 1], a1 = obuf[ob - 1], a2 = obuf[ob + CXC - 1];
            h8 a3 = obuf[ob + 2 * CXC - 1], a4 = obuf[ob + 3 * CXC - 1], a5 = obuf[ob + 4 * CXC - 1];
            if (rT) a0 = LO8;
            if (rB) a5 = LO8;
            h8 s12 = MAX2(a1, a2), s34 = MAX2(a3, a4);
            h8 Ml0 = MAX2(a0, s12), Ml1 = MAX2(s12, a3);
            h8 Ml2 = MAX2(a2, s34), Ml3 = MAX2(s34, a5);
            if (cL) { Ml0 = LO8; Ml1 = LO8; Ml2 = LO8; Ml3 = LO8; }
            // right column
            h8 b0 = obuf[ob - CXC + 1], b1 = obuf[ob + 1], b2 = obuf[ob + CXC + 1];
            h8 b3 = obuf[ob + 2 * CXC + 1], b4 = obuf[ob + 3 * CXC + 1], b5 = obuf[ob + 4 * CXC + 1];
            if (rT) b0 = LO8;
            if (rB) b5 = LO8;
            h8 t12 = MAX2(b1, b2), t34 = MAX2(b3, b4);
            h8 Mr0 = MAX2(b0, t12), Mr1 = MAX2(t12, b3);
            h8 Mr2 = MAX2(b2, t34), Mr3 = MAX2(t34, b5);
            if (cR) { Mr0 = LO8; Mr1 = LO8; Mr2 = LO8; Mr3 = LO8; }
            h8 o0 = MAX2(Mc0, MAX2(shl1(Mc0, dw3(Ml0)), shr1(Mc0, dw0(Mr0))));
            h8 o1 = MAX2(Mc1, MAX2(shl1(Mc1, dw3(Ml1)), shr1(Mc1, dw0(Mr1))));
            h8 o2 = MAX2(Mc2, MAX2(shl1(Mc2, dw3(Ml2)), shr1(Mc2, dw0(Mr2))));
            h8 o3 = MAX2(Mc3, MAX2(shl1(Mc3, dw3(Ml3)), shr1(Mc3, dw0(Mr3))));
            h8 d0 = MAX2(imv[0] - o0, Z8);
            h8 d1 = MAX2(imv[1] - o1, Z8);
            h8 d2 = MAX2(imv[2] - o2, Z8);
            h8 d3 = MAX2(imv[3] - o3, Z8);
            if (L == 1) { sk[0] = d0; sk[1] = d1; sk[2] = d2; sk[3] = d3; }
            else {
                sk[0] = sk[0] + MAX2(d0 - sk[0] * d0, Z8);
                sk[1] = sk[1] + MAX2(d1 - sk[1] * d1, Z8);
                sk[2] = sk[2] + MAX2(d2 - sk[2] * d2, Z8);
                sk[3] = sk[3] + MAX2(d3 - sk[3] * d3, Z8);
            }
            imv[0] = nm0; imv[1] = nm1; imv[2] = nm2; imv[3] = nm3;
        }
        // no barrier: open reads and next round's erode reads are both level L
    }

    // ---- final skO*skT exchange (T-open threads publish into bufO head) ----
    __syncthreads();
    if (oimg) {
#pragma unroll
        for (int k = 0; k < 4; ++k) bufO[4 * op + k] = sk[k];
    }
    __syncthreads();
    float I = 0.f, So = 0.f, St = 0.f;
    if (has_o && !oimg) {
#pragma unroll
        for (int k = 0; k < 4; ++k) {
            h8 t = bufO[4 * op + k];
#pragma unroll
            for (int j = 0; j < 8; ++j) {
                float a = (float)sk[k][j], b = (float)t[j];
                I += a * b; So += a; St += b;
            }
        }
    }

    // ---- block reduce 6 values (16 waves) ----
    float v6[6] = {d_inter, d_card, d_st, I, So, St};
#pragma unroll
    for (int q = 0; q < 6; ++q)
        for (int off = 32; off > 0; off >>= 1) v6[q] += __shfl_down(v6[q], off);
    int lane = tid & 63, w = tid >> 6;
    if (lane == 0) {
#pragma unroll
        for (int q = 0; q < 6; ++q) red[w * 6 + q] = v6[q];
    }
    __syncthreads();
    if (tid == 0) {
        int bid = (blockIdx.z * gridDim.y + blockIdx.y) * gridDim.x + blockIdx.x;
#pragma unroll
        for (int q = 0; q < 6; ++q) {
            float s = 0.f;
#pragma unroll
            for (int ww = 0; ww < 16; ++ww) s += red[ww * 6 + q];
            partials[q * NBLK + bid] = s;
        }
    }
}

__global__ __launch_bounds__(1024) void final_kernel(const float* __restrict__ partials,
                                                     float* __restrict__ out) {
    float s[6] = {0.f, 0.f, 0.f, 0.f, 0.f, 0.f};
    for (int i = threadIdx.x; i < NBLK; i += 1024) {
#pragma unroll
        for (int q = 0; q < 6; ++q) s[q] += partials[q * NBLK + i];
    }
#pragma unroll
    for (int q = 0; q < 6; ++q)
        for (int off = 32; off > 0; off >>= 1) s[q] += __shfl_down(s[q], off);
    __shared__ float red[96];
    int lane = threadIdx.x & 63, w = threadIdx.x >> 6;
    if (lane == 0) {
#pragma unroll
        for (int q = 0; q < 6; ++q) red[w * 6 + q] = s[q];
    }
    __syncthreads();
    if (threadIdx.x == 0) {
        float t[6];
#pragma unroll
        for (int q = 0; q < 6; ++q) {
            float a = 0.f;
#pragma unroll
            for (int ww = 0; ww < 16; ++ww) a += red[ww * 6 + q];
            t[q] = a;
        }
        float inter = t[0], card = t[1], sumt = t[2];
        float I = t[3], So = t[4], St = t[5];
        float score_d = (2.0f * inter + 1.0f) / fmaxf(card + 1.0f, 1e-7f);
        float dice = (1.0f - score_d) * (sumt > 0.0f ? 1.0f : 0.0f);
        float tprec = (I + 1.0f) / (So + 1.0f);
        float tsens = (I + 1.0f) / (St + 1.0f);
        float score_c = 2.0f * (tprec * tsens) / (tprec + tsens);
        float cl = (1.0f - score_c) * (St > 0.0f ? 1.0f : 0.0f);
        out[0] = 0.5f * dice + 0.5f * cl;
    }
}

extern "C" void kernel_launch(void* const* d_in, const int* in_sizes, int n_in,
                              void* d_out, int out_size, void* d_ws, size_t ws_size,
                              hipStream_t stream) {
    const float* logits = (const float*)d_in[0];
    const int* target = (const int*)d_in[1];
    float* out = (float*)d_out;
    float* partials = (float*)d_ws;  // 6*NBLK floats, fully overwritten each call

    dim3 grid(NBX, NBY, BATCH);
    cldice_mega_kernel<<<grid, NT, 0, stream>>>(logits, target, partials);
    final_kernel<<<1, 1024, 0, stream>>>(partials, out);
}